// Round 6
// baseline (477.141 us; speedup 1.0000x reference)
//
#include <hip/hip_runtime.h>
#include <hip/hip_bf16.h>

#define B_  4
#define S_  1024
#define DM_ 1024
#define H_  16
#define DK_ 64

typedef unsigned short u16;
typedef __attribute__((ext_vector_type(8))) short bf16x8;
typedef __attribute__((ext_vector_type(4))) float f32x4;

__device__ __forceinline__ float bf2f(u16 u) {
    union { unsigned int i; float f; } c;
    c.i = ((unsigned int)u) << 16;
    return c.f;
}
__device__ __forceinline__ u16 f2bf(float f) {
    union { float f; unsigned int i; } c;
    c.f = f;
    unsigned int x = c.i;
    unsigned int lsb = (x >> 16) & 1u;
    x += 0x7fffu + lsb;          // round-to-nearest-even
    return (u16)(x >> 16);
}
__device__ __forceinline__ u16 f2bf_fast(float f) {
    __hip_bfloat16 h = __float2bfloat16(f);   // HW cvt on gfx950, RNE
    return *reinterpret_cast<u16*>(&h);
}

// async global->LDS, 16B per lane; LDS dest = wave-uniform base + lane*16
__device__ __forceinline__ void async_ld16(const u16* g, u16* l) {
    __builtin_amdgcn_global_load_lds(
        (const __attribute__((address_space(1))) unsigned int*)(const void*)g,
        (__attribute__((address_space(3))) unsigned int*)(void*)l, 16, 0, 0);
}

// ---------------------------------------------------------------------------
// Runtime dtype detection (one wave). flag=1: inputs are fp32.
// ---------------------------------------------------------------------------
__global__ void detect_kernel(const u16* __restrict__ q, int* __restrict__ flag) {
    int lane = threadIdx.x & 63;
    int cnt = 0;
#pragma unroll
    for (int i = 0; i < 4; ++i) {
        u16 u = q[2 * (lane * 4 + i)];
        int e = (u >> 7) & 0xFF;
        cnt += (e >= 100 && e <= 140) ? 1 : 0;
    }
#pragma unroll
    for (int off = 1; off < 64; off <<= 1) cnt += __shfl_xor(cnt, off, 64);
    if (lane == 0) *flag = (cnt < 128) ? 1 : 0;
}

// ---------------------------------------------------------------------------
// Packed multi-tensor dtype normalization to bf16 (fp32-convert or copy).
// ---------------------------------------------------------------------------
#define NSEG 12
struct CvtArgs {
    const void* src[NSEG];
    void*       dst[NSEG];
    unsigned    off[NSEG + 1];
};

__global__ __launch_bounds__(256) void convert_kernel(
    CvtArgs a, unsigned total, const int* __restrict__ flag)
{
    unsigned v = blockIdx.x * 256 + threadIdx.x;
    if (v >= total) return;
    int s = 0;
    while (s < NSEG - 1 && v >= a.off[s + 1]) ++s;
    unsigned local = v - a.off[s];
    u16* dp = (u16*)a.dst[s] + (size_t)local * 8;
    if (*flag) {
        const float* sp = (const float*)a.src[s] + (size_t)local * 8;
        float4 x = *(const float4*)sp, y = *(const float4*)(sp + 4);
        u16 t[8] = {f2bf(x.x), f2bf(x.y), f2bf(x.z), f2bf(x.w),
                    f2bf(y.x), f2bf(y.y), f2bf(y.z), f2bf(y.w)};
        *(uint4*)dp = *(uint4*)t;
    } else {
        *(uint4*)dp = *(const uint4*)((const u16*)a.src[s] + (size_t)local * 8);
    }
}

// ---------------------------------------------------------------------------
// mask (int32) -> additive bf16 bias: 0 where mask!=0, -1e9 where mask==0.
// ---------------------------------------------------------------------------
__global__ __launch_bounds__(256) void maskbias_kernel(
    const int* __restrict__ mask, u16* __restrict__ mb)
{
    size_t i = ((size_t)blockIdx.x * 256 + threadIdx.x) * 8;
    int4 m0 = *(const int4*)&mask[i];
    int4 m1 = *(const int4*)&mask[i + 4];
    const u16 NEG = f2bf(-1e9f);
    u16 o[8];
    o[0] = m0.x ? 0 : NEG; o[1] = m0.y ? 0 : NEG;
    o[2] = m0.z ? 0 : NEG; o[3] = m0.w ? 0 : NEG;
    o[4] = m1.x ? 0 : NEG; o[5] = m1.y ? 0 : NEG;
    o[6] = m1.z ? 0 : NEG; o[7] = m1.w ? 0 : NEG;
    *(uint4*)&mb[i] = *(uint4*)o;
}

// ---------------------------------------------------------------------------
// Per-head transpose: Kp (b,s,h,d) -> KpT[((b*H+h)*DK + d)*S + s].
// ---------------------------------------------------------------------------
__global__ __launch_bounds__(256) void transpose_kernel(
    const u16* __restrict__ kp, u16* __restrict__ kpt)
{
    __shared__ u16 T[64][65];
    const int s0 = blockIdx.x * 64, h = blockIdx.y, b = blockIdx.z;
    const int tid = threadIdx.x;
    const size_t base = (size_t)b * S_ * DM_ + (size_t)h * DK_;
    for (int c = tid; c < 512; c += 256) {
        int row = c >> 3, cc = (c & 7) * 8;
        union { uint4 v; u16 u[8]; } x;
        x.v = *(const uint4*)&kp[base + (size_t)(s0 + row) * DM_ + cc];
#pragma unroll
        for (int j = 0; j < 8; ++j) T[row][cc + j] = x.u[j];
    }
    __syncthreads();
    const size_t baseT = (size_t)(b * H_ + h) * DK_ * S_;
    for (int c = tid; c < 512; c += 256) {
        int d = c >> 3, ss = (c & 7) * 8;
        u16 t[8];
#pragma unroll
        for (int j = 0; j < 8; ++j) t[j] = T[ss + j][d];
        *(uint4*)&kpt[baseT + (size_t)d * S_ + s0 + ss] = *(uint4*)t;
    }
}

// ---------------------------------------------------------------------------
// Batched descriptor: up to 4 (A, W, bias, C) GEMMs, selected by blockIdx.z.
// ---------------------------------------------------------------------------
struct GemmBatch {
    const u16* A[4];
    const u16* W[4];
    const void* bias[4];
    void* C[4];
};

// ---------------------------------------------------------------------------
// Big GEMM, m97 structure: 128x128 tile, BK=64, async global->LDS staging,
// XOR column-group swizzle. 4 waves in 2x2 quadrants (4x4 MFMAs each).
// ---------------------------------------------------------------------------
template<int ACT, int BIAS_DYN, int OUT_DYN>
__global__ __launch_bounds__(256, 3) void gemm_async_kernel(
    GemmBatch gb, int M, int N, int K, const int* __restrict__ flag)
{
    __shared__ __align__(16) u16 As[128][64];
    __shared__ __align__(16) u16 Ws[128][64];

    const int g = blockIdx.z;
    const u16* __restrict__ A = gb.A[g];
    const u16* __restrict__ W = gb.W[g];
    const void* biasp = gb.bias[g];
    void* Cp = gb.C[g];
    const int f = (BIAS_DYN || OUT_DYN) ? *flag : 0;

    const int m0   = blockIdx.y * 128;
    const int n0   = blockIdx.x * 128;
    const int tid  = threadIdx.x;
    const int w    = tid >> 6;
    const int lane = tid & 63;
    const int l16  = lane & 15;
    const int quad = lane >> 4;
    const int wr   = (w >> 1) * 64;
    const int wc   = (w & 1) * 64;

    const int srow = lane >> 3;
    const int sgrp = (lane & 7) ^ srow;

    f32x4 acc[4][4];
#pragma unroll
    for (int rt = 0; rt < 4; ++rt)
#pragma unroll
        for (int ct = 0; ct < 4; ++ct) acc[rt][ct] = (f32x4){0.f, 0.f, 0.f, 0.f};

    for (int k0 = 0; k0 < K; k0 += 64) {
#pragma unroll
        for (int s = 0; s < 4; ++s) {
            int seg = w * 4 + s;
            async_ld16(&A[(size_t)(m0 + seg * 8 + srow) * K + k0 + sgrp * 8],
                       &As[seg * 8][0]);
            async_ld16(&W[(size_t)(n0 + seg * 8 + srow) * K + k0 + sgrp * 8],
                       &Ws[seg * 8][0]);
        }
        __syncthreads();
#pragma unroll
        for (int kk = 0; kk < 2; ++kk) {
            const int p = (kk * 4 + quad) ^ (l16 & 7);
            bf16x8 av[4], bv[4];
#pragma unroll
            for (int rt = 0; rt < 4; ++rt)
                av[rt] = *(const bf16x8*)&As[wr + rt * 16 + l16][p * 8];
#pragma unroll
            for (int ct = 0; ct < 4; ++ct)
                bv[ct] = *(const bf16x8*)&Ws[wc + ct * 16 + l16][p * 8];
#pragma unroll
            for (int rt = 0; rt < 4; ++rt)
#pragma unroll
                for (int ct = 0; ct < 4; ++ct)
                    acc[rt][ct] = __builtin_amdgcn_mfma_f32_16x16x32_bf16(
                        av[rt], bv[ct], acc[rt][ct], 0, 0, 0);
        }
        __syncthreads();
    }

#pragma unroll
    for (int ct = 0; ct < 4; ++ct) {
        int col = n0 + wc + ct * 16 + l16;
        float bv = (BIAS_DYN && f) ? ((const float*)biasp)[col]
                                   : bf2f(((const u16*)biasp)[col]);
#pragma unroll
        for (int rt = 0; rt < 4; ++rt)
#pragma unroll
            for (int r = 0; r < 4; ++r) {
                int row = m0 + wr + rt * 16 + quad * 4 + r;
                float v = acc[rt][ct][r] + bv;
                if (ACT) v = v > 0.f ? v : 0.f;
                size_t idx = (size_t)row * N + col;
                if (OUT_DYN && f) ((float*)Cp)[idx] = v;
                else              ((u16*)Cp)[idx]   = f2bf(v);
            }
    }
}

// ---------------------------------------------------------------------------
// Small GEMM (N=K=64, memory-bound): 128x64 tile, batched.
// ---------------------------------------------------------------------------
template<int ACT, int BIAS_DYN, int OUT_DYN>
__global__ __launch_bounds__(256, 2) void gemm_small_kernel(
    GemmBatch gb, int M, int N, int K, const int* __restrict__ flag)
{
    __shared__ __align__(16) u16 As[128][72];
    __shared__ __align__(16) u16 Ws[64][72];

    const int g = blockIdx.z;
    const u16* __restrict__ A = gb.A[g];
    const u16* __restrict__ W = gb.W[g];
    const void* biasp = gb.bias[g];
    void* Cp = gb.C[g];
    const int f = (BIAS_DYN || OUT_DYN) ? *flag : 0;

    const int m0   = blockIdx.y * 128;
    const int n0   = blockIdx.x * 64;
    const int tid  = threadIdx.x;
    const int w    = tid >> 6;
    const int lane = tid & 63;
    const int l16  = lane & 15;
    const int quad = lane >> 4;

    f32x4 acc[2][4];
#pragma unroll
    for (int rt = 0; rt < 2; ++rt)
#pragma unroll
        for (int ct = 0; ct < 4; ++ct) acc[rt][ct] = (f32x4){0.f, 0.f, 0.f, 0.f};

    for (int k0 = 0; k0 < K; k0 += 64) {
#pragma unroll
        for (int c = tid; c < 1024; c += 256) {
            int row = c >> 3, cc = (c & 7) * 8;
            *(uint4*)&As[row][cc] = *(const uint4*)&A[(size_t)(m0 + row) * K + k0 + cc];
        }
#pragma unroll
        for (int c = tid; c < 512; c += 256) {
            int row = c >> 3, cc = (c & 7) * 8;
            *(uint4*)&Ws[row][cc] = *(const uint4*)&W[(size_t)(n0 + row) * K + k0 + cc];
        }
        __syncthreads();
#pragma unroll
        for (int kk = 0; kk < 2; ++kk) {
            bf16x8 a[2], b[4];
#pragma unroll
            for (int rt = 0; rt < 2; ++rt)
                a[rt] = *(const bf16x8*)&As[w * 32 + rt * 16 + l16][kk * 32 + quad * 8];
#pragma unroll
            for (int ct = 0; ct < 4; ++ct)
                b[ct] = *(const bf16x8*)&Ws[ct * 16 + l16][kk * 32 + quad * 8];
#pragma unroll
            for (int rt = 0; rt < 2; ++rt)
#pragma unroll
                for (int ct = 0; ct < 4; ++ct)
                    acc[rt][ct] = __builtin_amdgcn_mfma_f32_16x16x32_bf16(
                        a[rt], b[ct], acc[rt][ct], 0, 0, 0);
        }
        __syncthreads();
    }

#pragma unroll
    for (int ct = 0; ct < 4; ++ct) {
        int col = n0 + ct * 16 + l16;
        float bv = (BIAS_DYN && f) ? ((const float*)biasp)[col]
                                   : bf2f(((const u16*)biasp)[col]);
#pragma unroll
        for (int rt = 0; rt < 2; ++rt)
#pragma unroll
            for (int r = 0; r < 4; ++r) {
                int row = m0 + w * 32 + rt * 16 + quad * 4 + r;
                float v = acc[rt][ct][r] + bv;
                if (ACT) v = v > 0.f ? v : 0.f;
                size_t idx = (size_t)row * N + col;
                if (OUT_DYN && f) ((float*)Cp)[idx] = v;
                else              ((u16*)Cp)[idx]   = f2bf(v);
            }
    }
}

// ---------------------------------------------------------------------------
// Fused attention, flash-style, software-pipelined staging.
// Per K-tile: [bar] regs->LDS [bar] {issue next tile's global loads, then
// compute}. The compiler's vmcnt(0)-before-barrier drain thus lands AFTER
// the ~1500-cycle compute phase — global latency fully hidden.
// ---------------------------------------------------------------------------
__global__ __launch_bounds__(256, 4) void attn_kernel(
    const u16* __restrict__ q1, const u16* __restrict__ q2,
    const u16* __restrict__ kr, const u16* __restrict__ vr,
    const u16* __restrict__ kpt, const u16* __restrict__ mb,
    u16* __restrict__ om)
{
    __shared__ __align__(16) u16 krs[64][72];
    __shared__ __align__(16) u16 vrs[64][72];
    __shared__ __align__(16) u16 kts[64][72];   // KpT tile: rows d, cols k
    __shared__ __align__(16) u16 mbs[64][72];   // mask bias; P~ staging aliases

    const int qt   = blockIdx.x;
    const int h    = blockIdx.y;
    const int b    = blockIdx.z;
    const int q0   = qt * 64;
    const int tid  = threadIdx.x;
    const int w    = tid >> 6;
    const int lane = tid & 63;
    const int l16  = lane & 15;
    const int quad = lane >> 4;

    const size_t base  = (size_t)b * S_ * DM_ + (size_t)h * DK_;
    const size_t baseT = (size_t)(b * H_ + h) * DK_ * S_;

    // q fragments in registers: A[m=l16][k=quad*8+j]
    const int qrow = q0 + w * 16 + l16;
    bf16x8 a1[2], a2[2];
#pragma unroll
    for (int kk = 0; kk < 2; ++kk) {
        a1[kk] = *(const bf16x8*)&q1[base + (size_t)qrow * DM_ + kk * 32 + quad * 8];
        a2[kk] = *(const bf16x8*)&q2[base + (size_t)qrow * DM_ + kk * 32 + quad * 8];
    }

    // staging registers (tile prefetch): 2 chunks x 4 arrays
    uint4 rkr[2], rvr[2], rkt[2], rmb[2];
    const int c0row = tid >> 3, c0cc = (tid & 7) * 8;           // chunk 0
    const int c1row = (tid + 256) >> 3, c1cc = c0cc;            // chunk 1

    auto load_tile = [&](int kt) {
        const int k0 = kt * 64;
        rkr[0] = *(const uint4*)&kr[base + (size_t)(k0 + c0row) * DM_ + c0cc];
        rvr[0] = *(const uint4*)&vr[base + (size_t)(k0 + c0row) * DM_ + c0cc];
        rkt[0] = *(const uint4*)&kpt[baseT + (size_t)c0row * S_ + k0 + c0cc];
        rmb[0] = *(const uint4*)&mb[((size_t)b * S_ + q0 + c0row) * S_ + k0 + c0cc];
        rkr[1] = *(const uint4*)&kr[base + (size_t)(k0 + c1row) * DM_ + c1cc];
        rvr[1] = *(const uint4*)&vr[base + (size_t)(k0 + c1row) * DM_ + c1cc];
        rkt[1] = *(const uint4*)&kpt[baseT + (size_t)c1row * S_ + k0 + c1cc];
        rmb[1] = *(const uint4*)&mb[((size_t)b * S_ + q0 + c1row) * S_ + k0 + c1cc];
    };

    float m_run[4], l_run[4];
    f32x4 oacc[4];
#pragma unroll
    for (int r = 0; r < 4; ++r) { m_run[r] = -1e30f; l_run[r] = 0.f; }
#pragma unroll
    for (int ct = 0; ct < 4; ++ct) oacc[ct] = (f32x4){0.f, 0.f, 0.f, 0.f};

    load_tile(0);

    for (int kt = 0; kt < S_ / 64; ++kt) {
        __syncthreads();   // all waves done reading LDS (prior tile)
        *(uint4*)&krs[c0row][c0cc] = rkr[0];
        *(uint4*)&vrs[c0row][c0cc] = rvr[0];
        *(uint4*)&kts[c0row][c0cc] = rkt[0];
        *(uint4*)&mbs[c0row][c0cc] = rmb[0];
        *(uint4*)&krs[c1row][c1cc] = rkr[1];
        *(uint4*)&vrs[c1row][c1cc] = rvr[1];
        *(uint4*)&kts[c1row][c1cc] = rkt[1];
        *(uint4*)&mbs[c1row][c1cc] = rmb[1];
        __syncthreads();   // writes visible

        // prefetch next tile NOW — drains only at next iter's first barrier,
        // i.e. after the whole compute phase below.
        load_tile(kt < S_ / 64 - 1 ? kt + 1 : kt);

        f32x4 s1[4], s2[4];
#pragma unroll
        for (int ct = 0; ct < 4; ++ct) {
            s1[ct] = (f32x4){0.f, 0.f, 0.f, 0.f};
            s2[ct] = (f32x4){0.f, 0.f, 0.f, 0.f};
        }
#pragma unroll
        for (int kk = 0; kk < 2; ++kk) {
#pragma unroll
            for (int ct = 0; ct < 4; ++ct) {
                bf16x8 b1 = *(const bf16x8*)&krs[ct * 16 + l16][kk * 32 + quad * 8];
                bf16x8 b2 = *(const bf16x8*)&vrs[ct * 16 + l16][kk * 32 + quad * 8];
                s1[ct] = __builtin_amdgcn_mfma_f32_16x16x32_bf16(a1[kk], b1, s1[ct], 0, 0, 0);
                s2[ct] = __builtin_amdgcn_mfma_f32_16x16x32_bf16(a2[kk], b2, s2[ct], 0, 0, 0);
            }
        }

        float tmax[4] = {-1e30f, -1e30f, -1e30f, -1e30f};
#pragma unroll
        for (int ct = 0; ct < 4; ++ct)
#pragma unroll
            for (int r = 0; r < 4; ++r) {
                float v = s1[ct][r] + bf2f(mbs[w * 16 + quad * 4 + r][ct * 16 + l16]);
                s1[ct][r] = v;
                tmax[r] = fmaxf(tmax[r], v);
            }
#pragma unroll
        for (int off = 1; off < 16; off <<= 1)
#pragma unroll
            for (int r = 0; r < 4; ++r)
                tmax[r] = fmaxf(tmax[r], __shfl_xor(tmax[r], off, 64));

        float alpha[4], newm[4];
#pragma unroll
        for (int r = 0; r < 4; ++r) {
            newm[r]  = fmaxf(m_run[r], tmax[r]);
            alpha[r] = __expf(m_run[r] - newm[r]);
            m_run[r] = newm[r];
        }

        float psum[4] = {0.f, 0.f, 0.f, 0.f};
#pragma unroll
        for (int ct = 0; ct < 4; ++ct)
#pragma unroll
            for (int r = 0; r < 4; ++r) {
                float p = __expf(s1[ct][r] - newm[r]);
                psum[r] += p;
                mbs[w * 16 + quad * 4 + r][ct * 16 + l16] = f2bf_fast(p * s2[ct][r]);
            }
#pragma unroll
        for (int off = 1; off < 16; off <<= 1)
#pragma unroll
            for (int r = 0; r < 4; ++r)
                psum[r] += __shfl_xor(psum[r], off, 64);
#pragma unroll
        for (int r = 0; r < 4; ++r) l_run[r] = l_run[r] * alpha[r] + psum[r];
#pragma unroll
        for (int ct = 0; ct < 4; ++ct)
#pragma unroll
            for (int r = 0; r < 4; ++r) oacc[ct][r] *= alpha[r];

        // O += P~ @ Kp_tile (A from own wave's mbs rows; same-wave DS in-order)
#pragma unroll
        for (int kk = 0; kk < 2; ++kk) {
            bf16x8 a = *(const bf16x8*)&mbs[w * 16 + l16][kk * 32 + quad * 8];
#pragma unroll
            for (int ct = 0; ct < 4; ++ct) {
                bf16x8 bb = *(const bf16x8*)&kts[ct * 16 + l16][kk * 32 + quad * 8];
                oacc[ct] = __builtin_amdgcn_mfma_f32_16x16x32_bf16(a, bb, oacc[ct], 0, 0, 0);
            }
        }
    }

#pragma unroll
    for (int ct = 0; ct < 4; ++ct)
#pragma unroll
        for (int r = 0; r < 4; ++r) {
            int row = q0 + w * 16 + quad * 4 + r;
            int col = ct * 16 + l16;
            float v = oacc[ct][r] / l_run[r];
            om[base + (size_t)row * DM_ + col] = f2bf_fast(v);
        }
}

// ---------------------------------------------------------------------------
extern "C" void kernel_launch(void* const* d_in, const int* in_sizes, int n_in,
                              void* d_out, int out_size, void* d_ws, size_t ws_size,
                              hipStream_t stream)
{
    const void* query = d_in[0];
    const void* key   = d_in[1];
    const void* value = d_in[2];
    const int*  mask  = (const int*)d_in[3];
    const void* Wq  = d_in[4];  const void* bq  = d_in[5];
    const void* Wk  = d_in[6];  const void* bk  = d_in[7];
    const void* Wv  = d_in[8];  const void* bv  = d_in[9];
    const void* Wo  = d_in[10]; const void* bo  = d_in[11];
    const void* Wkl = d_in[12]; const void* bkl = d_in[13];
    const void* Wql = d_in[14]; const void* bql = d_in[15];
    const void* Wq2 = d_in[16]; const void* bq2 = d_in[17];
    const void* Wvl = d_in[18]; const void* bvl = d_in[19];
    const void* Wel = d_in[20]; const void* bel = d_in[21];

    int* flag = (int*)d_ws;
    u16* ws   = (u16*)((char*)d_ws + 16);
    const size_t BUF = (size_t)(B_ * S_) * DM_;   // 4M elems = 8 MB bf16
    u16* Qp  = ws + 0 * BUF;
    u16* Kp  = ws + 1 * BUF;
    u16* Vp  = ws + 2 * BUF;
    u16* krb = ws + 3 * BUF;
    u16* q1a = ws + 4 * BUF;
    u16* q1b = ws + 5 * BUF;
    u16* q2r = ws + 6 * BUF;
    u16* vrb = ws + 7 * BUF;
    u16* Om  = ws + 8 * BUF;
    u16* Qc  = ws + 9 * BUF;
    u16* Kc  = ws + 10 * BUF;
    u16* Vc  = ws + 11 * BUF;
    u16* Wbig = ws + 12 * BUF;
    u16* Wqc = Wbig + 0 * (size_t)(DM_ * DM_);
    u16* Wkc = Wbig + 1 * (size_t)(DM_ * DM_);
    u16* Wvc = Wbig + 2 * (size_t)(DM_ * DM_);
    u16* Woc = Wbig + 3 * (size_t)(DM_ * DM_);
    u16* Wsm = Wbig + 4 * (size_t)(DM_ * DM_);
    u16* Wklc = Wsm + 0 * (DK_ * DK_);
    u16* Wqlc = Wsm + 1 * (DK_ * DK_);
    u16* Welc = Wsm + 2 * (DK_ * DK_);
    u16* Wq2c = Wsm + 3 * (DK_ * DK_);
    u16* Wvlc = Wsm + 4 * (DK_ * DK_);
    u16* KpT = Vp;   // alias: Vp free after refinement batch
    u16* mb  = Kp;   // alias: Kp free after transpose

    const int M = B_ * S_;
    dim3 blk(256);

    detect_kernel<<<1, 64, 0, stream>>>((const u16*)query, flag);

    CvtArgs ca;
    const unsigned VIN = (unsigned)(BUF / 8);
    const unsigned VWB = (unsigned)(DM_ * DM_ / 8);
    const unsigned VWS = (unsigned)(DK_ * DK_ / 8);
    const void* srcs[NSEG] = {query, key, value, Wq, Wk, Wv, Wo, Wkl, Wql, Wel, Wq2, Wvl};
    void* dsts[NSEG] = {Qc, Kc, Vc, Wqc, Wkc, Wvc, Woc, Wklc, Wqlc, Welc, Wq2c, Wvlc};
    unsigned vcn[NSEG] = {VIN, VIN, VIN, VWB, VWB, VWB, VWB, VWS, VWS, VWS, VWS, VWS};
    unsigned off = 0;
    for (int i = 0; i < NSEG; ++i) { ca.src[i] = srcs[i]; ca.dst[i] = dsts[i]; ca.off[i] = off; off += vcn[i]; }
    ca.off[NSEG] = off;
    convert_kernel<<<dim3((off + 255) / 256), blk, 0, stream>>>(ca, off, flag);

    // Q/K/V projections batched (768 blocks -> 3/CU)
    GemmBatch gqkv = {};
    gqkv.A[0] = Qc;  gqkv.W[0] = Wqc; gqkv.bias[0] = bq; gqkv.C[0] = Qp;
    gqkv.A[1] = Kc;  gqkv.W[1] = Wkc; gqkv.bias[1] = bk; gqkv.C[1] = Kp;
    gqkv.A[2] = Vc;  gqkv.W[2] = Wvc; gqkv.bias[2] = bv; gqkv.C[2] = Vp;
    dim3 gBig(DM_ / 128, M / 128, 3);
    gemm_async_kernel<0,1,0><<<gBig, blk, 0, stream>>>(gqkv, M, DM_, DM_, flag);

    // 4 independent per-head refinements batched
    GemmBatch gref = {};
    gref.A[0] = Kp; gref.W[0] = Wklc; gref.bias[0] = bkl; gref.C[0] = krb;
    gref.A[1] = Qp; gref.W[1] = Wqlc; gref.bias[1] = bql; gref.C[1] = q1a;
    gref.A[2] = Qp; gref.W[2] = Wq2c; gref.bias[2] = bq2; gref.C[2] = q2r;
    gref.A[3] = Vp; gref.W[3] = Wvlc; gref.bias[3] = bvl; gref.C[3] = vrb;
    dim3 gSm(1, (M * H_) / 128, 4);
    gemm_small_kernel<1,1,0><<<gSm, blk, 0, stream>>>(gref, M * H_, DK_, DK_, flag);

    // dependent refinement: q1b = relu(q1a @ Wel^T + bel)
    GemmBatch gel = {};
    gel.A[0] = q1a; gel.W[0] = Welc; gel.bias[0] = bel; gel.C[0] = q1b;
    dim3 gS1(1, (M * H_) / 128, 1);
    gemm_small_kernel<1,1,0><<<gS1, blk, 0, stream>>>(gel, M * H_, DK_, DK_, flag);

    // Kp -> per-head transposed copy
    dim3 gT(S_ / 64, H_, B_);
    transpose_kernel<<<gT, blk, 0, stream>>>(Kp, KpT);

    // mask -> additive bf16 bias
    maskbias_kernel<<<dim3((B_ * S_ * S_) / (256 * 8)), blk, 0, stream>>>(mask, mb);

    // fused attention -> merged (B,S,DM) layout
    dim3 gA(S_ / 64, H_, B_);
    attn_kernel<<<gA, blk, 0, stream>>>(q1b, q2r, krb, vrb, KpT, mb, Om);

    // output projection -> d_out
    GemmBatch go = {};
    go.A[0] = Om; go.W[0] = Woc; go.bias[0] = bo; go.C[0] = (u16*)d_out;
    dim3 gO(DM_ / 128, M / 128, 1);
    gemm_async_kernel<0,1,1><<<gO, blk, 0, stream>>>(go, M, DM_, DM_, flag);
}

// Round 7
// 349.899 us; speedup vs baseline: 1.3637x; 1.3637x over previous
//
#include <hip/hip_runtime.h>
#include <hip/hip_bf16.h>

#define B_  4
#define S_  1024
#define DM_ 1024
#define H_  16
#define DK_ 64

typedef unsigned short u16;
typedef __attribute__((ext_vector_type(8))) short bf16x8;
typedef __attribute__((ext_vector_type(4))) float f32x4;

__device__ __forceinline__ float bf2f(u16 u) {
    union { unsigned int i; float f; } c;
    c.i = ((unsigned int)u) << 16;
    return c.f;
}
__device__ __forceinline__ u16 f2bf(float f) {
    union { float f; unsigned int i; } c;
    c.f = f;
    unsigned int x = c.i;
    unsigned int lsb = (x >> 16) & 1u;
    x += 0x7fffu + lsb;          // round-to-nearest-even
    return (u16)(x >> 16);
}
__device__ __forceinline__ u16 f2bf_fast(float f) {
    __hip_bfloat16 h = __float2bfloat16(f);   // HW cvt, RNE
    return *reinterpret_cast<u16*>(&h);
}

// async global->LDS, 16B per lane; LDS dest = wave-uniform base + lane*16
__device__ __forceinline__ void async_ld16(const u16* g, u16* l) {
    __builtin_amdgcn_global_load_lds(
        (const __attribute__((address_space(1))) unsigned int*)(const void*)g,
        (__attribute__((address_space(3))) unsigned int*)(void*)l, 16, 0, 0);
}

// ---------------------------------------------------------------------------
// Runtime dtype detection (one wave). flag=1: inputs are fp32.
// ---------------------------------------------------------------------------
__global__ void detect_kernel(const u16* __restrict__ q, int* __restrict__ flag) {
    int lane = threadIdx.x & 63;
    int cnt = 0;
#pragma unroll
    for (int i = 0; i < 4; ++i) {
        u16 u = q[2 * (lane * 4 + i)];
        int e = (u >> 7) & 0xFF;
        cnt += (e >= 100 && e <= 140) ? 1 : 0;
    }
#pragma unroll
    for (int off = 1; off < 64; off <<= 1) cnt += __shfl_xor(cnt, off, 64);
    if (lane == 0) *flag = (cnt < 128) ? 1 : 0;
}

// ---------------------------------------------------------------------------
// Packed multi-tensor dtype normalization to bf16 (fp32-convert or copy).
// ---------------------------------------------------------------------------
#define NSEG 12
struct CvtArgs {
    const void* src[NSEG];
    void*       dst[NSEG];
    unsigned    off[NSEG + 1];
};

__global__ __launch_bounds__(256) void convert_kernel(
    CvtArgs a, unsigned total, const int* __restrict__ flag)
{
    unsigned v = blockIdx.x * 256 + threadIdx.x;
    if (v >= total) return;
    int s = 0;
    while (s < NSEG - 1 && v >= a.off[s + 1]) ++s;
    unsigned local = v - a.off[s];
    u16* dp = (u16*)a.dst[s] + (size_t)local * 8;
    if (*flag) {
        const float* sp = (const float*)a.src[s] + (size_t)local * 8;
        float4 x = *(const float4*)sp, y = *(const float4*)(sp + 4);
        u16 t[8] = {f2bf(x.x), f2bf(x.y), f2bf(x.z), f2bf(x.w),
                    f2bf(y.x), f2bf(y.y), f2bf(y.z), f2bf(y.w)};
        *(uint4*)dp = *(uint4*)t;
    } else {
        *(uint4*)dp = *(const uint4*)((const u16*)a.src[s] + (size_t)local * 8);
    }
}

// ---------------------------------------------------------------------------
// Per-(b, k64-tile) mask flags: tflags[b*16+kt] = 1 iff any zero in
// mask[b][:, kt*64 .. kt*64+63]. 64 blocks, each scans 1024x64 ints.
// ---------------------------------------------------------------------------
__global__ __launch_bounds__(256) void maskflag_kernel(
    const int* __restrict__ mask, int* __restrict__ tflags)
{
    __shared__ int bad;
    const int kt = blockIdx.x, b = blockIdx.y;
    const int tid = threadIdx.x;
    if (tid == 0) bad = 0;
    __syncthreads();
    int ok = 1;
    for (int i = tid; i < 1024 * 16; i += 256) {
        int row = i >> 4, seg = i & 15;
        int4 m = *(const int4*)&mask[((size_t)b * S_ + row) * S_ + kt * 64 + seg * 4];
        ok &= (m.x != 0) & (m.y != 0) & (m.z != 0) & (m.w != 0);
    }
    if (!ok) bad = 1;   // benign race: all writers store 1
    __syncthreads();
    if (tid == 0) tflags[b * 16 + kt] = bad;
}

// ---------------------------------------------------------------------------
// Per-head transpose: Kp (b,s,h,d) -> KpT[((b*H+h)*DK + d)*S + s].
// ---------------------------------------------------------------------------
__global__ __launch_bounds__(256) void transpose_kernel(
    const u16* __restrict__ kp, u16* __restrict__ kpt)
{
    __shared__ u16 T[64][65];
    const int s0 = blockIdx.x * 64, h = blockIdx.y, b = blockIdx.z;
    const int tid = threadIdx.x;
    const size_t base = (size_t)b * S_ * DM_ + (size_t)h * DK_;
    for (int c = tid; c < 512; c += 256) {
        int row = c >> 3, cc = (c & 7) * 8;
        union { uint4 v; u16 u[8]; } x;
        x.v = *(const uint4*)&kp[base + (size_t)(s0 + row) * DM_ + cc];
#pragma unroll
        for (int j = 0; j < 8; ++j) T[row][cc + j] = x.u[j];
    }
    __syncthreads();
    const size_t baseT = (size_t)(b * H_ + h) * DK_ * S_;
    for (int c = tid; c < 512; c += 256) {
        int d = c >> 3, ss = (c & 7) * 8;
        u16 t[8];
#pragma unroll
        for (int j = 0; j < 8; ++j) t[j] = T[ss + j][d];
        *(uint4*)&kpt[baseT + (size_t)d * S_ + s0 + ss] = *(uint4*)t;
    }
}

// ---------------------------------------------------------------------------
// Batched descriptor: up to 4 (A, W, bias, C) GEMMs, selected by blockIdx.z.
// ---------------------------------------------------------------------------
struct GemmBatch {
    const u16* A[4];
    const u16* W[4];
    const void* bias[4];
    void* C[4];
};

// ---------------------------------------------------------------------------
// Big GEMM, m97 structure: 128x128 tile, BK=64, async global->LDS staging,
// XOR column-group swizzle. 4 waves in 2x2 quadrants (4x4 MFMAs each).
// ---------------------------------------------------------------------------
template<int ACT, int BIAS_DYN, int OUT_DYN>
__global__ __launch_bounds__(256, 3) void gemm_async_kernel(
    GemmBatch gb, int M, int N, int K, const int* __restrict__ flag)
{
    __shared__ __align__(16) u16 As[128][64];
    __shared__ __align__(16) u16 Ws[128][64];

    const int g = blockIdx.z;
    const u16* __restrict__ A = gb.A[g];
    const u16* __restrict__ W = gb.W[g];
    const void* biasp = gb.bias[g];
    void* Cp = gb.C[g];
    const int f = (BIAS_DYN || OUT_DYN) ? *flag : 0;

    const int m0   = blockIdx.y * 128;
    const int n0   = blockIdx.x * 128;
    const int tid  = threadIdx.x;
    const int w    = tid >> 6;
    const int lane = tid & 63;
    const int l16  = lane & 15;
    const int quad = lane >> 4;
    const int wr   = (w >> 1) * 64;
    const int wc   = (w & 1) * 64;

    const int srow = lane >> 3;
    const int sgrp = (lane & 7) ^ srow;

    f32x4 acc[4][4];
#pragma unroll
    for (int rt = 0; rt < 4; ++rt)
#pragma unroll
        for (int ct = 0; ct < 4; ++ct) acc[rt][ct] = (f32x4){0.f, 0.f, 0.f, 0.f};

    for (int k0 = 0; k0 < K; k0 += 64) {
#pragma unroll
        for (int s = 0; s < 4; ++s) {
            int seg = w * 4 + s;
            async_ld16(&A[(size_t)(m0 + seg * 8 + srow) * K + k0 + sgrp * 8],
                       &As[seg * 8][0]);
            async_ld16(&W[(size_t)(n0 + seg * 8 + srow) * K + k0 + sgrp * 8],
                       &Ws[seg * 8][0]);
        }
        __syncthreads();
#pragma unroll
        for (int kk = 0; kk < 2; ++kk) {
            const int p = (kk * 4 + quad) ^ (l16 & 7);
            bf16x8 av[4], bv[4];
#pragma unroll
            for (int rt = 0; rt < 4; ++rt)
                av[rt] = *(const bf16x8*)&As[wr + rt * 16 + l16][p * 8];
#pragma unroll
            for (int ct = 0; ct < 4; ++ct)
                bv[ct] = *(const bf16x8*)&Ws[wc + ct * 16 + l16][p * 8];
#pragma unroll
            for (int rt = 0; rt < 4; ++rt)
#pragma unroll
                for (int ct = 0; ct < 4; ++ct)
                    acc[rt][ct] = __builtin_amdgcn_mfma_f32_16x16x32_bf16(
                        av[rt], bv[ct], acc[rt][ct], 0, 0, 0);
        }
        __syncthreads();
    }

#pragma unroll
    for (int ct = 0; ct < 4; ++ct) {
        int col = n0 + wc + ct * 16 + l16;
        float bv = (BIAS_DYN && f) ? ((const float*)biasp)[col]
                                   : bf2f(((const u16*)biasp)[col]);
#pragma unroll
        for (int rt = 0; rt < 4; ++rt)
#pragma unroll
            for (int r = 0; r < 4; ++r) {
                int row = m0 + wr + rt * 16 + quad * 4 + r;
                float v = acc[rt][ct][r] + bv;
                if (ACT) v = v > 0.f ? v : 0.f;
                size_t idx = (size_t)row * N + col;
                if (OUT_DYN && f) ((float*)Cp)[idx] = v;
                else              ((u16*)Cp)[idx]   = f2bf(v);
            }
    }
}

// ---------------------------------------------------------------------------
// Small GEMM (N=K=64, memory-bound): 128x64 tile, batched.
// ---------------------------------------------------------------------------
template<int ACT, int BIAS_DYN, int OUT_DYN>
__global__ __launch_bounds__(256, 2) void gemm_small_kernel(
    GemmBatch gb, int M, int N, int K, const int* __restrict__ flag)
{
    __shared__ __align__(16) u16 As[128][72];
    __shared__ __align__(16) u16 Ws[64][72];

    const int g = blockIdx.z;
    const u16* __restrict__ A = gb.A[g];
    const u16* __restrict__ W = gb.W[g];
    const void* biasp = gb.bias[g];
    void* Cp = gb.C[g];
    const int f = (BIAS_DYN || OUT_DYN) ? *flag : 0;

    const int m0   = blockIdx.y * 128;
    const int n0   = blockIdx.x * 64;
    const int tid  = threadIdx.x;
    const int w    = tid >> 6;
    const int lane = tid & 63;
    const int l16  = lane & 15;
    const int quad = lane >> 4;

    f32x4 acc[2][4];
#pragma unroll
    for (int rt = 0; rt < 2; ++rt)
#pragma unroll
        for (int ct = 0; ct < 4; ++ct) acc[rt][ct] = (f32x4){0.f, 0.f, 0.f, 0.f};

    for (int k0 = 0; k0 < K; k0 += 64) {
#pragma unroll
        for (int c = tid; c < 1024; c += 256) {
            int row = c >> 3, cc = (c & 7) * 8;
            *(uint4*)&As[row][cc] = *(const uint4*)&A[(size_t)(m0 + row) * K + k0 + cc];
        }
#pragma unroll
        for (int c = tid; c < 512; c += 256) {
            int row = c >> 3, cc = (c & 7) * 8;
            *(uint4*)&Ws[row][cc] = *(const uint4*)&W[(size_t)(n0 + row) * K + k0 + cc];
        }
        __syncthreads();
#pragma unroll
        for (int kk = 0; kk < 2; ++kk) {
            bf16x8 a[2], b[4];
#pragma unroll
            for (int rt = 0; rt < 2; ++rt)
                a[rt] = *(const bf16x8*)&As[w * 32 + rt * 16 + l16][kk * 32 + quad * 8];
#pragma unroll
            for (int ct = 0; ct < 4; ++ct)
                b[ct] = *(const bf16x8*)&Ws[ct * 16 + l16][kk * 32 + quad * 8];
#pragma unroll
            for (int rt = 0; rt < 2; ++rt)
#pragma unroll
                for (int ct = 0; ct < 4; ++ct)
                    acc[rt][ct] = __builtin_amdgcn_mfma_f32_16x16x32_bf16(
                        a[rt], b[ct], acc[rt][ct], 0, 0, 0);
        }
        __syncthreads();
    }

#pragma unroll
    for (int ct = 0; ct < 4; ++ct) {
        int col = n0 + ct * 16 + l16;
        float bv = (BIAS_DYN && f) ? ((const float*)biasp)[col]
                                   : bf2f(((const u16*)biasp)[col]);
#pragma unroll
        for (int rt = 0; rt < 2; ++rt)
#pragma unroll
            for (int r = 0; r < 4; ++r) {
                int row = m0 + w * 32 + rt * 16 + quad * 4 + r;
                float v = acc[rt][ct][r] + bv;
                if (ACT) v = v > 0.f ? v : 0.f;
                size_t idx = (size_t)row * N + col;
                if (OUT_DYN && f) ((float*)Cp)[idx] = v;
                else              ((u16*)Cp)[idx]   = f2bf(v);
            }
    }
}

// ---------------------------------------------------------------------------
// Fused attention, flash-style. 128 q-rows per block (wave owns 32 q-rows,
// 2 row-tiles) so k-side B-fragments and staging are shared across 2x the
// FLOPs. Mask handled via per-(b,k-tile) flags: clean tiles (the common
// case) skip all mask work; dirty tiles read the int mask directly from
// global (correct fallback, wave-uniform branch).
// ---------------------------------------------------------------------------
__global__ __launch_bounds__(256, 2) void attn_kernel(
    const u16* __restrict__ q1, const u16* __restrict__ q2,
    const u16* __restrict__ kr, const u16* __restrict__ vr,
    const u16* __restrict__ kpt, const int* __restrict__ mask,
    const int* __restrict__ tflags, u16* __restrict__ om)
{
    __shared__ __align__(16) u16 krs[64][72];
    __shared__ __align__(16) u16 vrs[64][72];
    __shared__ __align__(16) u16 kts[64][72];      // KpT tile: rows d, cols k
    __shared__ __align__(16) u16 pts[4][32][72];   // per-wave P~ staging

    const int qt   = blockIdx.x;
    const int h    = blockIdx.y;
    const int b    = blockIdx.z;
    const int q0   = qt * 128;
    const int tid  = threadIdx.x;
    const int w    = tid >> 6;
    const int lane = tid & 63;
    const int l16  = lane & 15;
    const int quad = lane >> 4;

    const size_t base  = (size_t)b * S_ * DM_ + (size_t)h * DK_;
    const size_t baseT = (size_t)(b * H_ + h) * DK_ * S_;

    // q fragments in registers: A[m=l16][k=quad*8+j], 2 row-tiles
    bf16x8 a1[2][2], a2[2][2];
#pragma unroll
    for (int rt = 0; rt < 2; ++rt) {
        const int qrow = q0 + w * 32 + rt * 16 + l16;
#pragma unroll
        for (int kk = 0; kk < 2; ++kk) {
            a1[rt][kk] = *(const bf16x8*)&q1[base + (size_t)qrow * DM_ + kk * 32 + quad * 8];
            a2[rt][kk] = *(const bf16x8*)&q2[base + (size_t)qrow * DM_ + kk * 32 + quad * 8];
        }
    }

    float m_run[2][4], l_run[2][4];
    f32x4 oacc[2][4];
#pragma unroll
    for (int rt = 0; rt < 2; ++rt)
#pragma unroll
        for (int r = 0; r < 4; ++r) { m_run[rt][r] = -1e30f; l_run[rt][r] = 0.f; }
#pragma unroll
    for (int rt = 0; rt < 2; ++rt)
#pragma unroll
        for (int ct = 0; ct < 4; ++ct) oacc[rt][ct] = (f32x4){0.f, 0.f, 0.f, 0.f};

    for (int kt = 0; kt < S_ / 64; ++kt) {
        const int k0 = kt * 64;
        __syncthreads();   // all waves done with prior tile's LDS
        for (int c = tid; c < 512; c += 256) {
            int row = c >> 3, cc = (c & 7) * 8;
            *(uint4*)&krs[row][cc] = *(const uint4*)&kr[base + (size_t)(k0 + row) * DM_ + cc];
            *(uint4*)&vrs[row][cc] = *(const uint4*)&vr[base + (size_t)(k0 + row) * DM_ + cc];
            *(uint4*)&kts[row][cc] = *(const uint4*)&kpt[baseT + (size_t)row * S_ + k0 + cc];
        }
        __syncthreads();

        const int tf = tflags[b * 16 + kt];   // wave-uniform

        // QK: S1 = q1@kr^T, S2 = q2@vr^T; B-frags shared across row-tiles
        f32x4 s1[2][4], s2[2][4];
#pragma unroll
        for (int rt = 0; rt < 2; ++rt)
#pragma unroll
            for (int ct = 0; ct < 4; ++ct) {
                s1[rt][ct] = (f32x4){0.f, 0.f, 0.f, 0.f};
                s2[rt][ct] = (f32x4){0.f, 0.f, 0.f, 0.f};
            }
#pragma unroll
        for (int kk = 0; kk < 2; ++kk) {
            bf16x8 b1[4], b2[4];
#pragma unroll
            for (int ct = 0; ct < 4; ++ct) {
                b1[ct] = *(const bf16x8*)&krs[ct * 16 + l16][kk * 32 + quad * 8];
                b2[ct] = *(const bf16x8*)&vrs[ct * 16 + l16][kk * 32 + quad * 8];
            }
#pragma unroll
            for (int rt = 0; rt < 2; ++rt)
#pragma unroll
                for (int ct = 0; ct < 4; ++ct) {
                    s1[rt][ct] = __builtin_amdgcn_mfma_f32_16x16x32_bf16(
                        a1[rt][kk], b1[ct], s1[rt][ct], 0, 0, 0);
                    s2[rt][ct] = __builtin_amdgcn_mfma_f32_16x16x32_bf16(
                        a2[rt][kk], b2[ct], s2[rt][ct], 0, 0, 0);
                }
        }

        // mask fallback (never taken for all-ones mask; correct if taken)
        if (tf) {
#pragma unroll
            for (int rt = 0; rt < 2; ++rt)
#pragma unroll
                for (int ct = 0; ct < 4; ++ct)
#pragma unroll
                    for (int r = 0; r < 4; ++r) {
                        int qrow = q0 + w * 32 + rt * 16 + quad * 4 + r;
                        int kc   = k0 + ct * 16 + l16;
                        if (mask[((size_t)b * S_ + qrow) * S_ + kc] == 0)
                            s1[rt][ct][r] = -1e9f;
                    }
        }

        // online softmax per row-tile
        float tmax[2][4];
#pragma unroll
        for (int rt = 0; rt < 2; ++rt)
#pragma unroll
            for (int r = 0; r < 4; ++r) tmax[rt][r] = -1e30f;
#pragma unroll
        for (int rt = 0; rt < 2; ++rt)
#pragma unroll
            for (int ct = 0; ct < 4; ++ct)
#pragma unroll
                for (int r = 0; r < 4; ++r)
                    tmax[rt][r] = fmaxf(tmax[rt][r], s1[rt][ct][r]);
#pragma unroll
        for (int off = 1; off < 16; off <<= 1)
#pragma unroll
            for (int rt = 0; rt < 2; ++rt)
#pragma unroll
                for (int r = 0; r < 4; ++r)
                    tmax[rt][r] = fmaxf(tmax[rt][r], __shfl_xor(tmax[rt][r], off, 64));

        float alpha[2][4], newm[2][4];
#pragma unroll
        for (int rt = 0; rt < 2; ++rt)
#pragma unroll
            for (int r = 0; r < 4; ++r) {
                newm[rt][r]  = fmaxf(m_run[rt][r], tmax[rt][r]);
                alpha[rt][r] = __expf(m_run[rt][r] - newm[rt][r]);
                m_run[rt][r] = newm[rt][r];
            }

        float psum[2][4] = {};
#pragma unroll
        for (int rt = 0; rt < 2; ++rt)
#pragma unroll
            for (int ct = 0; ct < 4; ++ct)
#pragma unroll
                for (int r = 0; r < 4; ++r) {
                    float p = __expf(s1[rt][ct][r] - newm[rt][r]);
                    psum[rt][r] += p;
                    pts[w][rt * 16 + quad * 4 + r][ct * 16 + l16] =
                        f2bf_fast(p * s2[rt][ct][r]);
                }
#pragma unroll
        for (int off = 1; off < 16; off <<= 1)
#pragma unroll
            for (int rt = 0; rt < 2; ++rt)
#pragma unroll
                for (int r = 0; r < 4; ++r)
                    psum[rt][r] += __shfl_xor(psum[rt][r], off, 64);
#pragma unroll
        for (int rt = 0; rt < 2; ++rt)
#pragma unroll
            for (int r = 0; r < 4; ++r)
                l_run[rt][r] = l_run[rt][r] * alpha[rt][r] + psum[rt][r];
#pragma unroll
        for (int rt = 0; rt < 2; ++rt)
#pragma unroll
            for (int ct = 0; ct < 4; ++ct)
#pragma unroll
                for (int r = 0; r < 4; ++r) oacc[rt][ct][r] *= alpha[rt][r];

        // PV: O += P~ @ Kp_tile; kts B-frags loaded once, shared across rt
        {
            bf16x8 bb[2][4];
#pragma unroll
            for (int kk = 0; kk < 2; ++kk)
#pragma unroll
                for (int ct = 0; ct < 4; ++ct)
                    bb[kk][ct] = *(const bf16x8*)&kts[ct * 16 + l16][kk * 32 + quad * 8];
#pragma unroll
            for (int rt = 0; rt < 2; ++rt)
#pragma unroll
                for (int kk = 0; kk < 2; ++kk) {
                    bf16x8 a = *(const bf16x8*)&pts[w][rt * 16 + l16][kk * 32 + quad * 8];
#pragma unroll
                    for (int ct = 0; ct < 4; ++ct)
                        oacc[rt][ct] = __builtin_amdgcn_mfma_f32_16x16x32_bf16(
                            a, bb[kk][ct], oacc[rt][ct], 0, 0, 0);
                }
        }
    }

#pragma unroll
    for (int rt = 0; rt < 2; ++rt)
#pragma unroll
        for (int ct = 0; ct < 4; ++ct)
#pragma unroll
            for (int r = 0; r < 4; ++r) {
                int row = q0 + w * 32 + rt * 16 + quad * 4 + r;
                int col = ct * 16 + l16;
                float v = oacc[rt][ct][r] / l_run[rt][r];
                om[base + (size_t)row * DM_ + col] = f2bf_fast(v);
            }
}

// ---------------------------------------------------------------------------
extern "C" void kernel_launch(void* const* d_in, const int* in_sizes, int n_in,
                              void* d_out, int out_size, void* d_ws, size_t ws_size,
                              hipStream_t stream)
{
    const void* query = d_in[0];
    const void* key   = d_in[1];
    const void* value = d_in[2];
    const int*  mask  = (const int*)d_in[3];
    const void* Wq  = d_in[4];  const void* bq  = d_in[5];
    const void* Wk  = d_in[6];  const void* bk  = d_in[7];
    const void* Wv  = d_in[8];  const void* bv  = d_in[9];
    const void* Wo  = d_in[10]; const void* bo  = d_in[11];
    const void* Wkl = d_in[12]; const void* bkl = d_in[13];
    const void* Wql = d_in[14]; const void* bql = d_in[15];
    const void* Wq2 = d_in[16]; const void* bq2 = d_in[17];
    const void* Wvl = d_in[18]; const void* bvl = d_in[19];
    const void* Wel = d_in[20]; const void* bel = d_in[21];

    int* flag   = (int*)d_ws;
    int* tflags = (int*)d_ws + 4;                     // 64 ints
    u16* ws     = (u16*)((char*)d_ws + 512);
    const size_t BUF = (size_t)(B_ * S_) * DM_;       // 4M elems = 8 MB bf16
    u16* Qp  = ws + 0 * BUF;
    u16* Kp  = ws + 1 * BUF;
    u16* Vp  = ws + 2 * BUF;
    u16* krb = ws + 3 * BUF;
    u16* q1a = ws + 4 * BUF;
    u16* q1b = ws + 5 * BUF;
    u16* q2r = ws + 6 * BUF;
    u16* vrb = ws + 7 * BUF;
    u16* Om  = ws + 8 * BUF;
    u16* Qc  = ws + 9 * BUF;
    u16* Kc  = ws + 10 * BUF;
    u16* Vc  = ws + 11 * BUF;
    u16* Wbig = ws + 12 * BUF;
    u16* Wqc = Wbig + 0 * (size_t)(DM_ * DM_);
    u16* Wkc = Wbig + 1 * (size_t)(DM_ * DM_);
    u16* Wvc = Wbig + 2 * (size_t)(DM_ * DM_);
    u16* Woc = Wbig + 3 * (size_t)(DM_ * DM_);
    u16* Wsm = Wbig + 4 * (size_t)(DM_ * DM_);
    u16* Wklc = Wsm + 0 * (DK_ * DK_);
    u16* Wqlc = Wsm + 1 * (DK_ * DK_);
    u16* Welc = Wsm + 2 * (DK_ * DK_);
    u16* Wq2c = Wsm + 3 * (DK_ * DK_);
    u16* Wvlc = Wsm + 4 * (DK_ * DK_);
    u16* KpT = Vp;   // alias: Vp free after refinement batch

    const int M = B_ * S_;
    dim3 blk(256);

    detect_kernel<<<1, 64, 0, stream>>>((const u16*)query, flag);

    CvtArgs ca;
    const unsigned VIN = (unsigned)(BUF / 8);
    const unsigned VWB = (unsigned)(DM_ * DM_ / 8);
    const unsigned VWS = (unsigned)(DK_ * DK_ / 8);
    const void* srcs[NSEG] = {query, key, value, Wq, Wk, Wv, Wo, Wkl, Wql, Wel, Wq2, Wvl};
    void* dsts[NSEG] = {Qc, Kc, Vc, Wqc, Wkc, Wvc, Woc, Wklc, Wqlc, Welc, Wq2c, Wvlc};
    unsigned vcn[NSEG] = {VIN, VIN, VIN, VWB, VWB, VWB, VWB, VWS, VWS, VWS, VWS, VWS};
    unsigned off = 0;
    for (int i = 0; i < NSEG; ++i) { ca.src[i] = srcs[i]; ca.dst[i] = dsts[i]; ca.off[i] = off; off += vcn[i]; }
    ca.off[NSEG] = off;
    convert_kernel<<<dim3((off + 255) / 256), blk, 0, stream>>>(ca, off, flag);

    // mask -> per-(b, k-tile) any-zero flags
    maskflag_kernel<<<dim3(16, 4), blk, 0, stream>>>(mask, tflags);

    // Q/K/V projections batched (768 blocks -> 3/CU)
    GemmBatch gqkv = {};
    gqkv.A[0] = Qc;  gqkv.W[0] = Wqc; gqkv.bias[0] = bq; gqkv.C[0] = Qp;
    gqkv.A[1] = Kc;  gqkv.W[1] = Wkc; gqkv.bias[1] = bk; gqkv.C[1] = Kp;
    gqkv.A[2] = Vc;  gqkv.W[2] = Wvc; gqkv.bias[2] = bv; gqkv.C[2] = Vp;
    dim3 gBig(DM_ / 128, M / 128, 3);
    gemm_async_kernel<0,1,0><<<gBig, blk, 0, stream>>>(gqkv, M, DM_, DM_, flag);

    // 4 independent per-head refinements batched
    GemmBatch gref = {};
    gref.A[0] = Kp; gref.W[0] = Wklc; gref.bias[0] = bkl; gref.C[0] = krb;
    gref.A[1] = Qp; gref.W[1] = Wqlc; gref.bias[1] = bql; gref.C[1] = q1a;
    gref.A[2] = Qp; gref.W[2] = Wq2c; gref.bias[2] = bq2; gref.C[2] = q2r;
    gref.A[3] = Vp; gref.W[3] = Wvlc; gref.bias[3] = bvl; gref.C[3] = vrb;
    dim3 gSm(1, (M * H_) / 128, 4);
    gemm_small_kernel<1,1,0><<<gSm, blk, 0, stream>>>(gref, M * H_, DK_, DK_, flag);

    // dependent refinement: q1b = relu(q1a @ Wel^T + bel)
    GemmBatch gel = {};
    gel.A[0] = q1a; gel.W[0] = Welc; gel.bias[0] = bel; gel.C[0] = q1b;
    dim3 gS1(1, (M * H_) / 128, 1);
    gemm_small_kernel<1,1,0><<<gS1, blk, 0, stream>>>(gel, M * H_, DK_, DK_, flag);

    // Kp -> per-head transposed copy (Vp slot free after refinement batch)
    dim3 gT(S_ / 64, H_, B_);
    transpose_kernel<<<gT, blk, 0, stream>>>(Kp, KpT);

    // fused attention -> merged (B,S,DM) layout (128 q-rows per block)
    dim3 gA(S_ / 128, H_, B_);
    attn_kernel<<<gA, blk, 0, stream>>>(q1b, q2r, krb, vrb, KpT, mask, tflags, Om);

    // output projection -> d_out
    GemmBatch go = {};
    go.A[0] = Om; go.W[0] = Woc; go.bias[0] = bo; go.C[0] = (u16*)d_out;
    dim3 gO(DM_ / 128, M / 128, 1);
    gemm_async_kernel<0,1,1><<<gO, blk, 0, stream>>>(go, M, DM_, DM_, flag);
}

// Round 8
// 330.756 us; speedup vs baseline: 1.4426x; 1.0579x over previous
//
#include <hip/hip_runtime.h>
#include <hip/hip_bf16.h>

#define B_  4
#define S_  1024
#define DM_ 1024
#define H_  16
#define DK_ 64
#define LOG2E 1.4426950408889634f

typedef unsigned short u16;
typedef __attribute__((ext_vector_type(8))) short bf16x8;
typedef __attribute__((ext_vector_type(4))) float f32x4;

__device__ __forceinline__ float bf2f(u16 u) {
    union { unsigned int i; float f; } c;
    c.i = ((unsigned int)u) << 16;
    return c.f;
}
__device__ __forceinline__ u16 f2bf(float f) {
    union { float f; unsigned int i; } c;
    c.f = f;
    unsigned int x = c.i;
    unsigned int lsb = (x >> 16) & 1u;
    x += 0x7fffu + lsb;          // round-to-nearest-even
    return (u16)(x >> 16);
}
__device__ __forceinline__ u16 f2bf_fast(float f) {
    __hip_bfloat16 h = __float2bfloat16(f);   // HW cvt, RNE
    return *reinterpret_cast<u16*>(&h);
}

// async global->LDS, 16B per lane; LDS dest = wave-uniform base + lane*16
__device__ __forceinline__ void async_ld16(const u16* g, u16* l) {
    __builtin_amdgcn_global_load_lds(
        (const __attribute__((address_space(1))) unsigned int*)(const void*)g,
        (__attribute__((address_space(3))) unsigned int*)(void*)l, 16, 0, 0);
}

// ---------------------------------------------------------------------------
// Runtime dtype detection (one wave). flag=1: inputs are fp32.
// ---------------------------------------------------------------------------
__global__ void detect_kernel(const u16* __restrict__ q, int* __restrict__ flag) {
    int lane = threadIdx.x & 63;
    int cnt = 0;
#pragma unroll
    for (int i = 0; i < 4; ++i) {
        u16 u = q[2 * (lane * 4 + i)];
        int e = (u >> 7) & 0xFF;
        cnt += (e >= 100 && e <= 140) ? 1 : 0;
    }
#pragma unroll
    for (int off = 1; off < 64; off <<= 1) cnt += __shfl_xor(cnt, off, 64);
    if (lane == 0) *flag = (cnt < 128) ? 1 : 0;
}

// ---------------------------------------------------------------------------
// Packed multi-tensor fp32->bf16 conversion. Early-out when inputs are
// already bf16 (GEMMs then read the originals directly).
// ---------------------------------------------------------------------------
#define NSEG 12
struct CvtArgs {
    const void* src[NSEG];
    void*       dst[NSEG];
    unsigned    off[NSEG + 1];
};

__global__ __launch_bounds__(256) void convert_kernel(
    CvtArgs a, unsigned total, const int* __restrict__ flag)
{
    if (!*flag) return;   // bf16 inputs: nothing to convert (same work per call)
    unsigned v = blockIdx.x * 256 + threadIdx.x;
    if (v >= total) return;
    int s = 0;
    while (s < NSEG - 1 && v >= a.off[s + 1]) ++s;
    unsigned local = v - a.off[s];
    u16* dp = (u16*)a.dst[s] + (size_t)local * 8;
    const float* sp = (const float*)a.src[s] + (size_t)local * 8;
    float4 x = *(const float4*)sp, y = *(const float4*)(sp + 4);
    u16 t[8] = {f2bf(x.x), f2bf(x.y), f2bf(x.z), f2bf(x.w),
                f2bf(y.x), f2bf(y.y), f2bf(y.z), f2bf(y.w)};
    *(uint4*)dp = *(uint4*)t;
}

// ---------------------------------------------------------------------------
// Per-(b, k64-tile) mask flags. Grid (16,4,8): 512 blocks for full-BW scan.
// tflags zeroed via hipMemsetAsync before launch; dirty tiles atomicOr 1.
// ---------------------------------------------------------------------------
__global__ __launch_bounds__(256) void maskflag_kernel(
    const int* __restrict__ mask, int* __restrict__ tflags)
{
    const int kt = blockIdx.x, b = blockIdx.y, z = blockIdx.z;
    const int tid = threadIdx.x;
    int ok = 1;
#pragma unroll
    for (int i = tid; i < 128 * 16; i += 256) {
        int row = z * 128 + (i >> 4), seg = i & 15;
        int4 m = *(const int4*)&mask[((size_t)b * S_ + row) * S_ + kt * 64 + seg * 4];
        ok &= (m.x != 0) & (m.y != 0) & (m.z != 0) & (m.w != 0);
    }
    if (!ok) atomicOr(&tflags[b * 16 + kt], 1);
}

// ---------------------------------------------------------------------------
// Per-head transpose: Kp (b,s,h,d) -> KpT[((b*H+h)*DK + d)*S + s].
// ---------------------------------------------------------------------------
__global__ __launch_bounds__(256) void transpose_kernel(
    const u16* __restrict__ kp, u16* __restrict__ kpt)
{
    __shared__ u16 T[64][65];
    const int s0 = blockIdx.x * 64, h = blockIdx.y, b = blockIdx.z;
    const int tid = threadIdx.x;
    const size_t base = (size_t)b * S_ * DM_ + (size_t)h * DK_;
    for (int c = tid; c < 512; c += 256) {
        int row = c >> 3, cc = (c & 7) * 8;
        union { uint4 v; u16 u[8]; } x;
        x.v = *(const uint4*)&kp[base + (size_t)(s0 + row) * DM_ + cc];
#pragma unroll
        for (int j = 0; j < 8; ++j) T[row][cc + j] = x.u[j];
    }
    __syncthreads();
    const size_t baseT = (size_t)(b * H_ + h) * DK_ * S_;
    for (int c = tid; c < 512; c += 256) {
        int d = c >> 3, ss = (c & 7) * 8;
        u16 t[8];
#pragma unroll
        for (int j = 0; j < 8; ++j) t[j] = T[ss + j][d];
        *(uint4*)&kpt[baseT + (size_t)d * S_ + s0 + ss] = *(uint4*)t;
    }
}

// ---------------------------------------------------------------------------
// Batched GEMM descriptor; *0 pointers used when flag=0 (bf16 originals),
// *1 when flag=1 (converted copies). oscale applied after activation.
// ---------------------------------------------------------------------------
struct GemmBatch {
    const u16* A0[4]; const u16* A1[4];
    const u16* W0[4]; const u16* W1[4];
    const void* bias[4];
    void* C[4];
    float oscale[4];
};

// ---------------------------------------------------------------------------
// Big GEMM, m97 structure: 128x128 tile, BK=64, async global->LDS staging,
// XOR column-group swizzle. 4 waves in 2x2 quadrants (4x4 MFMAs each).
// ---------------------------------------------------------------------------
template<int ACT, int BIAS_DYN, int OUT_DYN>
__global__ __launch_bounds__(256, 3) void gemm_async_kernel(
    GemmBatch gb, int M, int N, int K, const int* __restrict__ flag)
{
    __shared__ __align__(16) u16 As[128][64];
    __shared__ __align__(16) u16 Ws[128][64];

    const int g = blockIdx.z;
    const int f = *flag;
    const u16* __restrict__ A = f ? gb.A1[g] : gb.A0[g];
    const u16* __restrict__ W = f ? gb.W1[g] : gb.W0[g];
    const void* biasp = gb.bias[g];
    void* Cp = gb.C[g];

    const int m0   = blockIdx.y * 128;
    const int n0   = blockIdx.x * 128;
    const int tid  = threadIdx.x;
    const int w    = tid >> 6;
    const int lane = tid & 63;
    const int l16  = lane & 15;
    const int quad = lane >> 4;
    const int wr   = (w >> 1) * 64;
    const int wc   = (w & 1) * 64;

    const int srow = lane >> 3;
    const int sgrp = (lane & 7) ^ srow;

    f32x4 acc[4][4];
#pragma unroll
    for (int rt = 0; rt < 4; ++rt)
#pragma unroll
        for (int ct = 0; ct < 4; ++ct) acc[rt][ct] = (f32x4){0.f, 0.f, 0.f, 0.f};

    for (int k0 = 0; k0 < K; k0 += 64) {
#pragma unroll
        for (int s = 0; s < 4; ++s) {
            int seg = w * 4 + s;
            async_ld16(&A[(size_t)(m0 + seg * 8 + srow) * K + k0 + sgrp * 8],
                       &As[seg * 8][0]);
            async_ld16(&W[(size_t)(n0 + seg * 8 + srow) * K + k0 + sgrp * 8],
                       &Ws[seg * 8][0]);
        }
        __syncthreads();
#pragma unroll
        for (int kk = 0; kk < 2; ++kk) {
            const int p = (kk * 4 + quad) ^ (l16 & 7);
            bf16x8 av[4], bv[4];
#pragma unroll
            for (int rt = 0; rt < 4; ++rt)
                av[rt] = *(const bf16x8*)&As[wr + rt * 16 + l16][p * 8];
#pragma unroll
            for (int ct = 0; ct < 4; ++ct)
                bv[ct] = *(const bf16x8*)&Ws[wc + ct * 16 + l16][p * 8];
#pragma unroll
            for (int rt = 0; rt < 4; ++rt)
#pragma unroll
                for (int ct = 0; ct < 4; ++ct)
                    acc[rt][ct] = __builtin_amdgcn_mfma_f32_16x16x32_bf16(
                        av[rt], bv[ct], acc[rt][ct], 0, 0, 0);
        }
        __syncthreads();
    }

#pragma unroll
    for (int ct = 0; ct < 4; ++ct) {
        int col = n0 + wc + ct * 16 + l16;
        float bv = (BIAS_DYN && f) ? ((const float*)biasp)[col]
                                   : bf2f(((const u16*)biasp)[col]);
#pragma unroll
        for (int rt = 0; rt < 4; ++rt)
#pragma unroll
            for (int r = 0; r < 4; ++r) {
                int row = m0 + wr + rt * 16 + quad * 4 + r;
                float v = acc[rt][ct][r] + bv;
                if (ACT) v = v > 0.f ? v : 0.f;
                size_t idx = (size_t)row * N + col;
                if (OUT_DYN && f) ((float*)Cp)[idx] = v;
                else              ((u16*)Cp)[idx]   = f2bf(v);
            }
    }
}

// ---------------------------------------------------------------------------
// Small GEMM (N=K=64, memory-bound): 128x64 tile, batched, output scale.
// ---------------------------------------------------------------------------
template<int ACT, int BIAS_DYN, int OUT_DYN>
__global__ __launch_bounds__(256, 2) void gemm_small_kernel(
    GemmBatch gb, int M, int N, int K, const int* __restrict__ flag)
{
    __shared__ __align__(16) u16 As[128][72];
    __shared__ __align__(16) u16 Ws[64][72];

    const int g = blockIdx.z;
    const int f = *flag;
    const u16* __restrict__ A = f ? gb.A1[g] : gb.A0[g];
    const u16* __restrict__ W = f ? gb.W1[g] : gb.W0[g];
    const void* biasp = gb.bias[g];
    void* Cp = gb.C[g];
    const float osc = gb.oscale[g];

    const int m0   = blockIdx.y * 128;
    const int n0   = blockIdx.x * 64;
    const int tid  = threadIdx.x;
    const int w    = tid >> 6;
    const int lane = tid & 63;
    const int l16  = lane & 15;
    const int quad = lane >> 4;

    f32x4 acc[2][4];
#pragma unroll
    for (int rt = 0; rt < 2; ++rt)
#pragma unroll
        for (int ct = 0; ct < 4; ++ct) acc[rt][ct] = (f32x4){0.f, 0.f, 0.f, 0.f};

    for (int k0 = 0; k0 < K; k0 += 64) {
#pragma unroll
        for (int c = tid; c < 1024; c += 256) {
            int row = c >> 3, cc = (c & 7) * 8;
            *(uint4*)&As[row][cc] = *(const uint4*)&A[(size_t)(m0 + row) * K + k0 + cc];
        }
#pragma unroll
        for (int c = tid; c < 512; c += 256) {
            int row = c >> 3, cc = (c & 7) * 8;
            *(uint4*)&Ws[row][cc] = *(const uint4*)&W[(size_t)(n0 + row) * K + k0 + cc];
        }
        __syncthreads();
#pragma unroll
        for (int kk = 0; kk < 2; ++kk) {
            bf16x8 a[2], b[4];
#pragma unroll
            for (int rt = 0; rt < 2; ++rt)
                a[rt] = *(const bf16x8*)&As[w * 32 + rt * 16 + l16][kk * 32 + quad * 8];
#pragma unroll
            for (int ct = 0; ct < 4; ++ct)
                b[ct] = *(const bf16x8*)&Ws[ct * 16 + l16][kk * 32 + quad * 8];
#pragma unroll
            for (int rt = 0; rt < 2; ++rt)
#pragma unroll
                for (int ct = 0; ct < 4; ++ct)
                    acc[rt][ct] = __builtin_amdgcn_mfma_f32_16x16x32_bf16(
                        a[rt], b[ct], acc[rt][ct], 0, 0, 0);
        }
        __syncthreads();
    }

#pragma unroll
    for (int ct = 0; ct < 4; ++ct) {
        int col = n0 + ct * 16 + l16;
        float bv = (BIAS_DYN && f) ? ((const float*)biasp)[col]
                                   : bf2f(((const u16*)biasp)[col]);
#pragma unroll
        for (int rt = 0; rt < 2; ++rt)
#pragma unroll
            for (int r = 0; r < 4; ++r) {
                int row = m0 + w * 32 + rt * 16 + quad * 4 + r;
                float v = acc[rt][ct][r] + bv;
                if (ACT) v = v > 0.f ? v : 0.f;
                v *= osc;
                size_t idx = (size_t)row * N + col;
                if (OUT_DYN && f) ((float*)Cp)[idx] = v;
                else              ((u16*)Cp)[idx]   = f2bf(v);
            }
    }
}

// ---------------------------------------------------------------------------
// Fused attention. 128 q-rows/block, wave owns 32 rows (2 row-tiles).
// K-loop restructured: async global_load_lds double-buffer, ONE barrier per
// iter — next tile's loads issue right after the barrier, so the vmcnt(0)
// drain before the next barrier lands after the full compute phase.
// Scores arrive in log2 domain (q1 pre-scaled by log2e) -> native exp2f.
// ---------------------------------------------------------------------------
__global__ __launch_bounds__(256, 2) void attn_kernel(
    const u16* __restrict__ q1, const u16* __restrict__ q2,
    const u16* __restrict__ kr, const u16* __restrict__ vr,
    const u16* __restrict__ kpt, const int* __restrict__ mask,
    const int* __restrict__ tflags, u16* __restrict__ om)
{
    __shared__ __align__(16) u16 kbuf[2][3][64][64];  // [buf][kr,vr,kts][row][col^swz]
    __shared__ __align__(16) u16 pts[4][32][72];      // per-wave P~ staging

    const int qt   = blockIdx.x;
    const int h    = blockIdx.y;
    const int b    = blockIdx.z;
    const int q0   = qt * 128;
    const int tid  = threadIdx.x;
    const int w    = tid >> 6;
    const int lane = tid & 63;
    const int l16  = lane & 15;
    const int quad = lane >> 4;
    const int pb   = l16 & 7;

    const size_t base  = (size_t)b * S_ * DM_ + (size_t)h * DK_;
    const size_t baseT = (size_t)(b * H_ + h) * DK_ * S_;

    const int srow = lane >> 3;
    const int sgrp = (lane & 7) ^ srow;

    // 24 (tensor,seg8) units, 6 per wave; all indices wave-uniform.
    auto stage = [&](int kt, int bsel) {
        const int k0 = kt * 64;
#pragma unroll
        for (int j = 0; j < 6; ++j) {
            int idx = w * 6 + j;
            int t = idx >> 3, s = idx & 7;
            const u16* g;
            if (t == 0)      g = &kr[base + (size_t)(k0 + s * 8 + srow) * DM_ + sgrp * 8];
            else if (t == 1) g = &vr[base + (size_t)(k0 + s * 8 + srow) * DM_ + sgrp * 8];
            else             g = &kpt[baseT + (size_t)(s * 8 + srow) * S_ + k0 + sgrp * 8];
            async_ld16(g, &kbuf[bsel][t][s * 8][0]);
        }
    };

    // q fragments in registers: A[m=l16][k=quad*8+j], 2 row-tiles
    bf16x8 a1[2][2], a2[2][2];
#pragma unroll
    for (int rt = 0; rt < 2; ++rt) {
        const int qrow = q0 + w * 32 + rt * 16 + l16;
#pragma unroll
        for (int kk = 0; kk < 2; ++kk) {
            a1[rt][kk] = *(const bf16x8*)&q1[base + (size_t)qrow * DM_ + kk * 32 + quad * 8];
            a2[rt][kk] = *(const bf16x8*)&q2[base + (size_t)qrow * DM_ + kk * 32 + quad * 8];
        }
    }

    float m_run[2][4], l_run[2][4];
    f32x4 oacc[2][4];
#pragma unroll
    for (int rt = 0; rt < 2; ++rt)
#pragma unroll
        for (int r = 0; r < 4; ++r) { m_run[rt][r] = -1e30f; l_run[rt][r] = 0.f; }
#pragma unroll
    for (int rt = 0; rt < 2; ++rt)
#pragma unroll
        for (int ct = 0; ct < 4; ++ct) oacc[rt][ct] = (f32x4){0.f, 0.f, 0.f, 0.f};

    stage(0, 0);

    for (int kt = 0; kt < S_ / 64; ++kt) {
        const int cur = kt & 1;
        const int k0 = kt * 64;
        __syncthreads();   // drains tile-kt loads; frees buf[cur^1] for prefetch
        if (kt < S_ / 64 - 1) stage(kt + 1, cur ^ 1);

        const int tf = tflags[b * 16 + kt];   // wave-uniform

        // QK: S1 = q1@kr^T (log2 domain), S2 = q2@vr^T
        f32x4 s1[2][4], s2[2][4];
#pragma unroll
        for (int rt = 0; rt < 2; ++rt)
#pragma unroll
            for (int ct = 0; ct < 4; ++ct) {
                s1[rt][ct] = (f32x4){0.f, 0.f, 0.f, 0.f};
                s2[rt][ct] = (f32x4){0.f, 0.f, 0.f, 0.f};
            }
#pragma unroll
        for (int kk = 0; kk < 2; ++kk) {
            bf16x8 b1[4], b2[4];
#pragma unroll
            for (int ct = 0; ct < 4; ++ct) {
                const int p = (kk * 4 + quad) ^ pb;
                b1[ct] = *(const bf16x8*)&kbuf[cur][0][ct * 16 + l16][p * 8];
                b2[ct] = *(const bf16x8*)&kbuf[cur][1][ct * 16 + l16][p * 8];
            }
#pragma unroll
            for (int rt = 0; rt < 2; ++rt)
#pragma unroll
                for (int ct = 0; ct < 4; ++ct) {
                    s1[rt][ct] = __builtin_amdgcn_mfma_f32_16x16x32_bf16(
                        a1[rt][kk], b1[ct], s1[rt][ct], 0, 0, 0);
                    s2[rt][ct] = __builtin_amdgcn_mfma_f32_16x16x32_bf16(
                        a2[rt][kk], b2[ct], s2[rt][ct], 0, 0, 0);
                }
        }

        // mask fallback (wave-uniform branch; never taken for all-ones mask)
        if (tf) {
#pragma unroll
            for (int rt = 0; rt < 2; ++rt)
#pragma unroll
                for (int ct = 0; ct < 4; ++ct)
#pragma unroll
                    for (int r = 0; r < 4; ++r) {
                        int qrow = q0 + w * 32 + rt * 16 + quad * 4 + r;
                        int kc   = k0 + ct * 16 + l16;
                        if (mask[((size_t)b * S_ + qrow) * S_ + kc] == 0)
                            s1[rt][ct][r] = -1e9f;
                    }
        }

        // online softmax (log2 domain)
        float tmax[2][4];
#pragma unroll
        for (int rt = 0; rt < 2; ++rt)
#pragma unroll
            for (int r = 0; r < 4; ++r) tmax[rt][r] = -1e30f;
#pragma unroll
        for (int rt = 0; rt < 2; ++rt)
#pragma unroll
            for (int ct = 0; ct < 4; ++ct)
#pragma unroll
                for (int r = 0; r < 4; ++r)
                    tmax[rt][r] = fmaxf(tmax[rt][r], s1[rt][ct][r]);
#pragma unroll
        for (int off = 1; off < 16; off <<= 1)
#pragma unroll
            for (int rt = 0; rt < 2; ++rt)
#pragma unroll
                for (int r = 0; r < 4; ++r)
                    tmax[rt][r] = fmaxf(tmax[rt][r], __shfl_xor(tmax[rt][r], off, 64));

        float alpha[2][4], newm[2][4];
#pragma unroll
        for (int rt = 0; rt < 2; ++rt)
#pragma unroll
            for (int r = 0; r < 4; ++r) {
                newm[rt][r]  = fmaxf(m_run[rt][r], tmax[rt][r]);
                alpha[rt][r] = exp2f(m_run[rt][r] - newm[rt][r]);
                m_run[rt][r] = newm[rt][r];
            }

        float psum[2][4] = {};
#pragma unroll
        for (int rt = 0; rt < 2; ++rt)
#pragma unroll
            for (int ct = 0; ct < 4; ++ct)
#pragma unroll
                for (int r = 0; r < 4; ++r) {
                    float p = exp2f(s1[rt][ct][r] - newm[rt][r]);
                    psum[rt][r] += p;
                    pts[w][rt * 16 + quad * 4 + r][ct * 16 + l16] =
                        f2bf_fast(p * s2[rt][ct][r]);
                }
#pragma unroll
        for (int off = 1; off < 16; off <<= 1)
#pragma unroll
            for (int rt = 0; rt < 2; ++rt)
#pragma unroll
                for (int r = 0; r < 4; ++r)
                    psum[rt][r] += __shfl_xor(psum[rt][r], off, 64);
#pragma unroll
        for (int rt = 0; rt < 2; ++rt)
#pragma unroll
            for (int r = 0; r < 4; ++r)
                l_run[rt][r] = l_run[rt][r] * alpha[rt][r] + psum[rt][r];
#pragma unroll
        for (int rt = 0; rt < 2; ++rt)
#pragma unroll
            for (int ct = 0; ct < 4; ++ct)
#pragma unroll
                for (int r = 0; r < 4; ++r) oacc[rt][ct][r] *= alpha[rt][r];

        // PV: O += P~ @ Kp_tile (pts same-wave DS in-order; kts shared over rt)
        {
            bf16x8 bb[2][4];
#pragma unroll
            for (int kk = 0; kk < 2; ++kk)
#pragma unroll
                for (int ct = 0; ct < 4; ++ct) {
                    const int p = (kk * 4 + quad) ^ pb;
                    bb[kk][ct] = *(const bf16x8*)&kbuf[cur][2][ct * 16 + l16][p * 8];
                }
#pragma unroll
            for (int rt = 0; rt < 2; ++rt)
#pragma unroll
                for (int kk = 0; kk < 2; ++kk) {
                    bf16x8 a = *(const bf16x8*)&pts[w][rt * 16 + l16][kk * 32 + quad * 8];
#pragma unroll
                    for (int ct = 0; ct < 4; ++ct)
                        oacc[rt][ct] = __builtin_amdgcn_mfma_f32_16x16x32_bf16(
                            a, bb[kk][ct], oacc[rt][ct], 0, 0, 0);
                }
        }
    }

#pragma unroll
    for (int rt = 0; rt < 2; ++rt)
#pragma unroll
        for (int ct = 0; ct < 4; ++ct)
#pragma unroll
            for (int r = 0; r < 4; ++r) {
                int row = q0 + w * 32 + rt * 16 + quad * 4 + r;
                int col = ct * 16 + l16;
                float v = oacc[rt][ct][r] / l_run[rt][r];
                om[base + (size_t)row * DM_ + col] = f2bf_fast(v);
            }
}

// ---------------------------------------------------------------------------
extern "C" void kernel_launch(void* const* d_in, const int* in_sizes, int n_in,
                              void* d_out, int out_size, void* d_ws, size_t ws_size,
                              hipStream_t stream)
{
    const void* query = d_in[0];
    const void* key   = d_in[1];
    const void* value = d_in[2];
    const int*  mask  = (const int*)d_in[3];
    const void* Wq  = d_in[4];  const void* bq  = d_in[5];
    const void* Wk  = d_in[6];  const void* bk  = d_in[7];
    const void* Wv  = d_in[8];  const void* bv  = d_in[9];
    const void* Wo  = d_in[10]; const void* bo  = d_in[11];
    const void* Wkl = d_in[12]; const void* bkl = d_in[13];
    const void* Wql = d_in[14]; const void* bql = d_in[15];
    const void* Wq2 = d_in[16]; const void* bq2 = d_in[17];
    const void* Wvl = d_in[18]; const void* bvl = d_in[19];
    const void* Wel = d_in[20]; const void* bel = d_in[21];

    int* flag   = (int*)d_ws;
    int* tflags = (int*)d_ws + 4;                     // 64 ints
    u16* ws     = (u16*)((char*)d_ws + 512);
    const size_t BUF = (size_t)(B_ * S_) * DM_;       // 4M elems = 8 MB bf16
    u16* Qp  = ws + 0 * BUF;
    u16* Kp  = ws + 1 * BUF;
    u16* Vp  = ws + 2 * BUF;
    u16* krb = ws + 3 * BUF;
    u16* q1a = ws + 4 * BUF;
    u16* q1b = ws + 5 * BUF;
    u16* q2r = ws + 6 * BUF;
    u16* vrb = ws + 7 * BUF;
    u16* Om  = ws + 8 * BUF;
    u16* Qc  = ws + 9 * BUF;
    u16* Kc  = ws + 10 * BUF;
    u16* Vc  = ws + 11 * BUF;
    u16* Wbig = ws + 12 * BUF;
    u16* Wqc = Wbig + 0 * (size_t)(DM_ * DM_);
    u16* Wkc = Wbig + 1 * (size_t)(DM_ * DM_);
    u16* Wvc = Wbig + 2 * (size_t)(DM_ * DM_);
    u16* Woc = Wbig + 3 * (size_t)(DM_ * DM_);
    u16* Wsm = Wbig + 4 * (size_t)(DM_ * DM_);
    u16* Wklc = Wsm + 0 * (DK_ * DK_);
    u16* Wqlc = Wsm + 1 * (DK_ * DK_);
    u16* Welc = Wsm + 2 * (DK_ * DK_);
    u16* Wq2c = Wsm + 3 * (DK_ * DK_);
    u16* Wvlc = Wsm + 4 * (DK_ * DK_);
    u16* KpT = Vp;   // alias: Vp free after refinement batch

    const int M = B_ * S_;
    dim3 blk(256);

    detect_kernel<<<1, 64, 0, stream>>>((const u16*)query, flag);

    CvtArgs ca;
    const unsigned VIN = (unsigned)(BUF / 8);
    const unsigned VWB = (unsigned)(DM_ * DM_ / 8);
    const unsigned VWS = (unsigned)(DK_ * DK_ / 8);
    const void* srcs[NSEG] = {query, key, value, Wq, Wk, Wv, Wo, Wkl, Wql, Wel, Wq2, Wvl};
    void* dsts[NSEG] = {Qc, Kc, Vc, Wqc, Wkc, Wvc, Woc, Wklc, Wqlc, Welc, Wq2c, Wvlc};
    unsigned vcn[NSEG] = {VIN, VIN, VIN, VWB, VWB, VWB, VWB, VWS, VWS, VWS, VWS, VWS};
    unsigned off = 0;
    for (int i = 0; i < NSEG; ++i) { ca.src[i] = srcs[i]; ca.dst[i] = dsts[i]; ca.off[i] = off; off += vcn[i]; }
    ca.off[NSEG] = off;
    convert_kernel<<<dim3((off + 255) / 256), blk, 0, stream>>>(ca, off, flag);

    // mask -> per-(b,k-tile) any-zero flags (zeroed async, 512-block scan)
    hipMemsetAsync(tflags, 0, 64 * sizeof(int), stream);
    maskflag_kernel<<<dim3(16, 4, 8), blk, 0, stream>>>(mask, tflags);

    // Q/K/V projections batched (768 blocks -> 3/CU)
    GemmBatch gqkv = {};
    gqkv.A0[0] = (const u16*)query; gqkv.A1[0] = Qc;
    gqkv.A0[1] = (const u16*)key;   gqkv.A1[1] = Kc;
    gqkv.A0[2] = (const u16*)value; gqkv.A1[2] = Vc;
    gqkv.W0[0] = (const u16*)Wq; gqkv.W1[0] = Wqc;
    gqkv.W0[1] = (const u16*)Wk; gqkv.W1[1] = Wkc;
    gqkv.W0[2] = (const u16*)Wv; gqkv.W1[2] = Wvc;
    gqkv.bias[0] = bq; gqkv.bias[1] = bk; gqkv.bias[2] = bv;
    gqkv.C[0] = Qp; gqkv.C[1] = Kp; gqkv.C[2] = Vp;
    dim3 gBig(DM_ / 128, M / 128, 3);
    gemm_async_kernel<0,1,0><<<gBig, blk, 0, stream>>>(gqkv, M, DM_, DM_, flag);

    // 4 independent per-head refinements batched
    GemmBatch gref = {};
    gref.A0[0] = gref.A1[0] = Kp; gref.W0[0] = (const u16*)Wkl; gref.W1[0] = Wklc;
    gref.A0[1] = gref.A1[1] = Qp; gref.W0[1] = (const u16*)Wql; gref.W1[1] = Wqlc;
    gref.A0[2] = gref.A1[2] = Qp; gref.W0[2] = (const u16*)Wq2; gref.W1[2] = Wq2c;
    gref.A0[3] = gref.A1[3] = Vp; gref.W0[3] = (const u16*)Wvl; gref.W1[3] = Wvlc;
    gref.bias[0] = bkl; gref.bias[1] = bql; gref.bias[2] = bq2; gref.bias[3] = bvl;
    gref.C[0] = krb; gref.C[1] = q1a; gref.C[2] = q2r; gref.C[3] = vrb;
    gref.oscale[0] = gref.oscale[1] = gref.oscale[2] = gref.oscale[3] = 1.0f;
    dim3 gSm(1, (M * H_) / 128, 4);
    gemm_small_kernel<1,1,0><<<gSm, blk, 0, stream>>>(gref, M * H_, DK_, DK_, flag);

    // dependent refinement: q1b = relu(q1a @ Wel^T + bel) * log2(e)
    GemmBatch gel = {};
    gel.A0[0] = gel.A1[0] = q1a; gel.W0[0] = (const u16*)Wel; gel.W1[0] = Welc;
    gel.bias[0] = bel; gel.C[0] = q1b; gel.oscale[0] = LOG2E;
    dim3 gS1(1, (M * H_) / 128, 1);
    gemm_small_kernel<1,1,0><<<gS1, blk, 0, stream>>>(gel, M * H_, DK_, DK_, flag);

    // Kp -> per-head transposed copy (Vp slot free after refinement batch)
    dim3 gT(S_ / 64, H_, B_);
    transpose_kernel<<<gT, blk, 0, stream>>>(Kp, KpT);

    // fused attention -> merged (B,S,DM) layout (128 q-rows per block)
    dim3 gA(S_ / 128, H_, B_);
    attn_kernel<<<gA, blk, 0, stream>>>(q1b, q2r, krb, vrb, KpT, mask, tflags, Om);

    // output projection -> d_out
    GemmBatch go = {};
    go.A0[0] = go.A1[0] = Om; go.W0[0] = (const u16*)Wo; go.W1[0] = Woc;
    go.bias[0] = bo; go.C[0] = (u16*)d_out;
    dim3 gO(DM_ / 128, M / 128, 1);
    gemm_async_kernel<0,1,1><<<gO, blk, 0, stream>>>(go, M, DM_, DM_, flag);
}

// Round 9
// 316.688 us; speedup vs baseline: 1.5067x; 1.0444x over previous
//
#include <hip/hip_runtime.h>
#include <hip/hip_bf16.h>

#define B_  4
#define S_  1024
#define DM_ 1024
#define H_  16
#define DK_ 64
#define LOG2E 1.4426950408889634f

typedef unsigned short u16;
typedef __attribute__((ext_vector_type(8))) short bf16x8;
typedef __attribute__((ext_vector_type(4))) float f32x4;

__device__ __forceinline__ float bf2f(u16 u) {
    union { unsigned int i; float f; } c;
    c.i = ((unsigned int)u) << 16;
    return c.f;
}
__device__ __forceinline__ u16 f2bf(float f) {
    union { float f; unsigned int i; } c;
    c.f = f;
    unsigned int x = c.i;
    unsigned int lsb = (x >> 16) & 1u;
    x += 0x7fffu + lsb;          // round-to-nearest-even
    return (u16)(x >> 16);
}
__device__ __forceinline__ u16 f2bf_fast(float f) {
    __hip_bfloat16 h = __float2bfloat16(f);   // HW cvt, RNE
    return *reinterpret_cast<u16*>(&h);
}

// async global->LDS, 16B per lane; LDS dest = wave-uniform base + lane*16
__device__ __forceinline__ void async_ld16(const u16* g, u16* l) {
    __builtin_amdgcn_global_load_lds(
        (const __attribute__((address_space(1))) unsigned int*)(const void*)g,
        (__attribute__((address_space(3))) unsigned int*)(void*)l, 16, 0, 0);
}

// ---------------------------------------------------------------------------
// Runtime dtype detection (one wave). flag=1: inputs are fp32.
// ---------------------------------------------------------------------------
__global__ void detect_kernel(const u16* __restrict__ q, int* __restrict__ flag) {
    int lane = threadIdx.x & 63;
    int cnt = 0;
#pragma unroll
    for (int i = 0; i < 4; ++i) {
        u16 u = q[2 * (lane * 4 + i)];
        int e = (u >> 7) & 0xFF;
        cnt += (e >= 100 && e <= 140) ? 1 : 0;
    }
#pragma unroll
    for (int off = 1; off < 64; off <<= 1) cnt += __shfl_xor(cnt, off, 64);
    if (lane == 0) *flag = (cnt < 128) ? 1 : 0;
}

// ---------------------------------------------------------------------------
// Fused prep: blocks [0,512) scan mask -> per-(b,k64-tile) any-zero flags
// (tflags pre-zeroed via hipMemsetAsync; dirty -> atomicOr 1). Blocks >= 512
// do packed fp32->bf16 conversion (early-out when inputs already bf16).
// ---------------------------------------------------------------------------
#define NSEG 12
struct CvtArgs {
    const void* src[NSEG];
    void*       dst[NSEG];
    unsigned    off[NSEG + 1];
};

__global__ __launch_bounds__(256) void prep_kernel(
    CvtArgs a, unsigned total, const int* __restrict__ flag,
    const int* __restrict__ mask, int* __restrict__ tflags)
{
    const int tid = threadIdx.x;
    if (blockIdx.x < 512) {
        const int bx = blockIdx.x;
        const int kt = bx & 15, b = (bx >> 4) & 3, z = bx >> 6;
        int ok = 1;
#pragma unroll
        for (int i = tid; i < 128 * 16; i += 256) {
            int row = z * 128 + (i >> 4), seg = i & 15;
            int4 m = *(const int4*)&mask[((size_t)b * S_ + row) * S_ + kt * 64 + seg * 4];
            ok &= (m.x != 0) & (m.y != 0) & (m.z != 0) & (m.w != 0);
        }
        if (!ok) atomicOr(&tflags[b * 16 + kt], 1);
        return;
    }
    if (!*flag) return;   // bf16 inputs: GEMMs read originals directly
    unsigned v = (blockIdx.x - 512) * 256 + tid;
    if (v >= total) return;
    int s = 0;
    while (s < NSEG - 1 && v >= a.off[s + 1]) ++s;
    unsigned local = v - a.off[s];
    u16* dp = (u16*)a.dst[s] + (size_t)local * 8;
    const float* sp = (const float*)a.src[s] + (size_t)local * 8;
    float4 x = *(const float4*)sp, y = *(const float4*)(sp + 4);
    u16 t[8] = {f2bf(x.x), f2bf(x.y), f2bf(x.z), f2bf(x.w),
                f2bf(y.x), f2bf(y.y), f2bf(y.z), f2bf(y.w)};
    *(uint4*)dp = *(uint4*)t;
}

// ---------------------------------------------------------------------------
// Per-head transpose: Kp (b,s,h,d) -> KpT[((b*H+h)*DK + d)*S + s].
// ---------------------------------------------------------------------------
__global__ __launch_bounds__(256) void transpose_kernel(
    const u16* __restrict__ kp, u16* __restrict__ kpt)
{
    __shared__ u16 T[64][65];
    const int s0 = blockIdx.x * 64, h = blockIdx.y, b = blockIdx.z;
    const int tid = threadIdx.x;
    const size_t base = (size_t)b * S_ * DM_ + (size_t)h * DK_;
    for (int c = tid; c < 512; c += 256) {
        int row = c >> 3, cc = (c & 7) * 8;
        union { uint4 v; u16 u[8]; } x;
        x.v = *(const uint4*)&kp[base + (size_t)(s0 + row) * DM_ + cc];
#pragma unroll
        for (int j = 0; j < 8; ++j) T[row][cc + j] = x.u[j];
    }
    __syncthreads();
    const size_t baseT = (size_t)(b * H_ + h) * DK_ * S_;
    for (int c = tid; c < 512; c += 256) {
        int d = c >> 3, ss = (c & 7) * 8;
        u16 t[8];
#pragma unroll
        for (int j = 0; j < 8; ++j) t[j] = T[ss + j][d];
        *(uint4*)&kpt[baseT + (size_t)d * S_ + s0 + ss] = *(uint4*)t;
    }
}

// ---------------------------------------------------------------------------
// Batched GEMM descriptor; *0 pointers used when flag=0 (bf16 originals),
// *1 when flag=1 (converted copies). chain[g]: fuse a second row-local
// 64x64 GEMM (W2, bias2): C = relu(relu(A@W^T+b)@W2^T+b2)*oscale.
// ---------------------------------------------------------------------------
struct GemmBatch {
    const u16* A0[4]; const u16* A1[4];
    const u16* W0[4]; const u16* W1[4];
    const u16* W20[4]; const u16* W21[4];
    const void* bias[4];
    const void* bias2[4];
    void* C[4];
    float oscale[4];
    int chain[4];
};

// ---------------------------------------------------------------------------
// Big GEMM, m97 structure: 128x128 tile, BK=64, async global->LDS staging,
// XOR column-group swizzle. 4 waves in 2x2 quadrants (4x4 MFMAs each).
// ---------------------------------------------------------------------------
template<int ACT, int BIAS_DYN, int OUT_DYN>
__global__ __launch_bounds__(256, 3) void gemm_async_kernel(
    GemmBatch gb, int M, int N, int K, const int* __restrict__ flag)
{
    __shared__ __align__(16) u16 As[128][64];
    __shared__ __align__(16) u16 Ws[128][64];

    const int g = blockIdx.z;
    const int f = *flag;
    const u16* __restrict__ A = f ? gb.A1[g] : gb.A0[g];
    const u16* __restrict__ W = f ? gb.W1[g] : gb.W0[g];
    const void* biasp = gb.bias[g];
    void* Cp = gb.C[g];

    const int m0   = blockIdx.y * 128;
    const int n0   = blockIdx.x * 128;
    const int tid  = threadIdx.x;
    const int w    = tid >> 6;
    const int lane = tid & 63;
    const int l16  = lane & 15;
    const int quad = lane >> 4;
    const int wr   = (w >> 1) * 64;
    const int wc   = (w & 1) * 64;

    const int srow = lane >> 3;
    const int sgrp = (lane & 7) ^ srow;

    f32x4 acc[4][4];
#pragma unroll
    for (int rt = 0; rt < 4; ++rt)
#pragma unroll
        for (int ct = 0; ct < 4; ++ct) acc[rt][ct] = (f32x4){0.f, 0.f, 0.f, 0.f};

    for (int k0 = 0; k0 < K; k0 += 64) {
#pragma unroll
        for (int s = 0; s < 4; ++s) {
            int seg = w * 4 + s;
            async_ld16(&A[(size_t)(m0 + seg * 8 + srow) * K + k0 + sgrp * 8],
                       &As[seg * 8][0]);
            async_ld16(&W[(size_t)(n0 + seg * 8 + srow) * K + k0 + sgrp * 8],
                       &Ws[seg * 8][0]);
        }
        __syncthreads();
#pragma unroll
        for (int kk = 0; kk < 2; ++kk) {
            const int p = (kk * 4 + quad) ^ (l16 & 7);
            bf16x8 av[4], bv[4];
#pragma unroll
            for (int rt = 0; rt < 4; ++rt)
                av[rt] = *(const bf16x8*)&As[wr + rt * 16 + l16][p * 8];
#pragma unroll
            for (int ct = 0; ct < 4; ++ct)
                bv[ct] = *(const bf16x8*)&Ws[wc + ct * 16 + l16][p * 8];
#pragma unroll
            for (int rt = 0; rt < 4; ++rt)
#pragma unroll
                for (int ct = 0; ct < 4; ++ct)
                    acc[rt][ct] = __builtin_amdgcn_mfma_f32_16x16x32_bf16(
                        av[rt], bv[ct], acc[rt][ct], 0, 0, 0);
        }
        __syncthreads();
    }

#pragma unroll
    for (int ct = 0; ct < 4; ++ct) {
        int col = n0 + wc + ct * 16 + l16;
        float bv = (BIAS_DYN && f) ? ((const float*)biasp)[col]
                                   : bf2f(((const u16*)biasp)[col]);
#pragma unroll
        for (int rt = 0; rt < 4; ++rt)
#pragma unroll
            for (int r = 0; r < 4; ++r) {
                int row = m0 + wr + rt * 16 + quad * 4 + r;
                float v = acc[rt][ct][r] + bv;
                if (ACT) v = v > 0.f ? v : 0.f;
                size_t idx = (size_t)row * N + col;
                if (OUT_DYN && f) ((float*)Cp)[idx] = v;
                else              ((u16*)Cp)[idx]   = f2bf(v);
            }
    }
}

// ---------------------------------------------------------------------------
// Small GEMM (N=K=64): 128x64 tile, batched. chain[g]=1 fuses a second
// row-local 64x64 GEMM via LDS round-trip (As reused for stage-1 output).
// ---------------------------------------------------------------------------
template<int ACT, int BIAS_DYN, int OUT_DYN>
__global__ __launch_bounds__(256, 2) void gemm_small_kernel(
    GemmBatch gb, int M, int N, int K, const int* __restrict__ flag)
{
    __shared__ __align__(16) u16 As[128][72];
    __shared__ __align__(16) u16 Ws[64][72];

    const int g = blockIdx.z;
    const int f = *flag;
    const u16* __restrict__ A = f ? gb.A1[g] : gb.A0[g];
    const u16* __restrict__ W = f ? gb.W1[g] : gb.W0[g];
    const void* biasp = gb.bias[g];
    void* Cp = gb.C[g];
    const float osc = gb.oscale[g];
    const int chain = gb.chain[g];

    const int m0   = blockIdx.y * 128;
    const int n0   = blockIdx.x * 64;
    const int tid  = threadIdx.x;
    const int w    = tid >> 6;
    const int lane = tid & 63;
    const int l16  = lane & 15;
    const int quad = lane >> 4;

    f32x4 acc[2][4];
#pragma unroll
    for (int rt = 0; rt < 2; ++rt)
#pragma unroll
        for (int ct = 0; ct < 4; ++ct) acc[rt][ct] = (f32x4){0.f, 0.f, 0.f, 0.f};

    for (int k0 = 0; k0 < K; k0 += 64) {
#pragma unroll
        for (int c = tid; c < 1024; c += 256) {
            int row = c >> 3, cc = (c & 7) * 8;
            *(uint4*)&As[row][cc] = *(const uint4*)&A[(size_t)(m0 + row) * K + k0 + cc];
        }
#pragma unroll
        for (int c = tid; c < 512; c += 256) {
            int row = c >> 3, cc = (c & 7) * 8;
            *(uint4*)&Ws[row][cc] = *(const uint4*)&W[(size_t)(n0 + row) * K + k0 + cc];
        }
        __syncthreads();
#pragma unroll
        for (int kk = 0; kk < 2; ++kk) {
            bf16x8 a[2], b[4];
#pragma unroll
            for (int rt = 0; rt < 2; ++rt)
                a[rt] = *(const bf16x8*)&As[w * 32 + rt * 16 + l16][kk * 32 + quad * 8];
#pragma unroll
            for (int ct = 0; ct < 4; ++ct)
                b[ct] = *(const bf16x8*)&Ws[ct * 16 + l16][kk * 32 + quad * 8];
#pragma unroll
            for (int rt = 0; rt < 2; ++rt)
#pragma unroll
                for (int ct = 0; ct < 4; ++ct)
                    acc[rt][ct] = __builtin_amdgcn_mfma_f32_16x16x32_bf16(
                        a[rt], b[ct], acc[rt][ct], 0, 0, 0);
        }
        __syncthreads();
    }

    if (!chain) {
#pragma unroll
        for (int ct = 0; ct < 4; ++ct) {
            int col = n0 + ct * 16 + l16;
            float bv = (BIAS_DYN && f) ? ((const float*)biasp)[col]
                                       : bf2f(((const u16*)biasp)[col]);
#pragma unroll
            for (int rt = 0; rt < 2; ++rt)
#pragma unroll
                for (int r = 0; r < 4; ++r) {
                    int row = m0 + w * 32 + rt * 16 + quad * 4 + r;
                    float v = acc[rt][ct][r] + bv;
                    if (ACT) v = v > 0.f ? v : 0.f;
                    v *= osc;
                    size_t idx = (size_t)row * N + col;
                    if (OUT_DYN && f) ((float*)Cp)[idx] = v;
                    else              ((u16*)Cp)[idx]   = f2bf(v);
                }
        }
    } else {
        // stage W2 into Ws (K-loop's final barrier makes As/Ws free)
        const u16* __restrict__ W2 = f ? gb.W21[g] : gb.W20[g];
#pragma unroll
        for (int c = tid; c < 512; c += 256) {
            int row = c >> 3, cc = (c & 7) * 8;
            *(uint4*)&Ws[row][cc] = *(const uint4*)&W2[(size_t)row * 64 + cc];
        }
        // stage-1 epilogue (bias1 + relu, bf16) into As rows owned by this wave
#pragma unroll
        for (int ct = 0; ct < 4; ++ct) {
            int col = ct * 16 + l16;
            float bv = (BIAS_DYN && f) ? ((const float*)biasp)[col]
                                       : bf2f(((const u16*)biasp)[col]);
#pragma unroll
            for (int rt = 0; rt < 2; ++rt)
#pragma unroll
                for (int r = 0; r < 4; ++r) {
                    float v = acc[rt][ct][r] + bv;
                    v = v > 0.f ? v : 0.f;
                    As[w * 32 + rt * 16 + quad * 4 + r][col] = f2bf(v);
                }
        }
        __syncthreads();   // Ws2 visible (As rows are same-wave, in-order)

        f32x4 acc2[2][4];
#pragma unroll
        for (int rt = 0; rt < 2; ++rt)
#pragma unroll
            for (int ct = 0; ct < 4; ++ct) acc2[rt][ct] = (f32x4){0.f, 0.f, 0.f, 0.f};
#pragma unroll
        for (int kk = 0; kk < 2; ++kk) {
            bf16x8 a[2], b[4];
#pragma unroll
            for (int rt = 0; rt < 2; ++rt)
                a[rt] = *(const bf16x8*)&As[w * 32 + rt * 16 + l16][kk * 32 + quad * 8];
#pragma unroll
            for (int ct = 0; ct < 4; ++ct)
                b[ct] = *(const bf16x8*)&Ws[ct * 16 + l16][kk * 32 + quad * 8];
#pragma unroll
            for (int rt = 0; rt < 2; ++rt)
#pragma unroll
                for (int ct = 0; ct < 4; ++ct)
                    acc2[rt][ct] = __builtin_amdgcn_mfma_f32_16x16x32_bf16(
                        a[rt], b[ct], acc2[rt][ct], 0, 0, 0);
        }
#pragma unroll
        for (int ct = 0; ct < 4; ++ct) {
            int col = ct * 16 + l16;
            float bv2 = (BIAS_DYN && f) ? ((const float*)gb.bias2[g])[col]
                                        : bf2f(((const u16*)gb.bias2[g])[col]);
#pragma unroll
            for (int rt = 0; rt < 2; ++rt)
#pragma unroll
                for (int r = 0; r < 4; ++r) {
                    int row = m0 + w * 32 + rt * 16 + quad * 4 + r;
                    float v = acc2[rt][ct][r] + bv2;
                    v = v > 0.f ? v : 0.f;
                    v *= osc;
                    ((u16*)Cp)[(size_t)row * N + col] = f2bf(v);
                }
        }
    }
}

// ---------------------------------------------------------------------------
// Fused attention (R7 structure: 2-barrier VGPR staging — the single-barrier
// global_load_lds variant forces a vmcnt(0) drain inside compute, R8 −20%).
// 128 q-rows/block, wave owns 32 rows (2 row-tiles); exp2-domain softmax
// (q1 pre-scaled by log2e). Mask via per-(b,k-tile) flags; dirty tiles read
// mask from global (wave-uniform branch, never taken for all-ones mask).
// ---------------------------------------------------------------------------
__global__ __launch_bounds__(256, 2) void attn_kernel(
    const u16* __restrict__ q1, const u16* __restrict__ q2,
    const u16* __restrict__ kr, const u16* __restrict__ vr,
    const u16* __restrict__ kpt, const int* __restrict__ mask,
    const int* __restrict__ tflags, u16* __restrict__ om)
{
    __shared__ __align__(16) u16 krs[64][72];
    __shared__ __align__(16) u16 vrs[64][72];
    __shared__ __align__(16) u16 kts[64][72];      // KpT tile: rows d, cols k
    __shared__ __align__(16) u16 pts[4][32][72];   // per-wave P~ staging

    const int qt   = blockIdx.x;
    const int h    = blockIdx.y;
    const int b    = blockIdx.z;
    const int q0   = qt * 128;
    const int tid  = threadIdx.x;
    const int w    = tid >> 6;
    const int lane = tid & 63;
    const int l16  = lane & 15;
    const int quad = lane >> 4;

    const size_t base  = (size_t)b * S_ * DM_ + (size_t)h * DK_;
    const size_t baseT = (size_t)(b * H_ + h) * DK_ * S_;

    // q fragments in registers: A[m=l16][k=quad*8+j], 2 row-tiles
    bf16x8 a1[2][2], a2[2][2];
#pragma unroll
    for (int rt = 0; rt < 2; ++rt) {
        const int qrow = q0 + w * 32 + rt * 16 + l16;
#pragma unroll
        for (int kk = 0; kk < 2; ++kk) {
            a1[rt][kk] = *(const bf16x8*)&q1[base + (size_t)qrow * DM_ + kk * 32 + quad * 8];
            a2[rt][kk] = *(const bf16x8*)&q2[base + (size_t)qrow * DM_ + kk * 32 + quad * 8];
        }
    }

    float m_run[2][4], l_run[2][4];
    f32x4 oacc[2][4];
#pragma unroll
    for (int rt = 0; rt < 2; ++rt)
#pragma unroll
        for (int r = 0; r < 4; ++r) { m_run[rt][r] = -1e30f; l_run[rt][r] = 0.f; }
#pragma unroll
    for (int rt = 0; rt < 2; ++rt)
#pragma unroll
        for (int ct = 0; ct < 4; ++ct) oacc[rt][ct] = (f32x4){0.f, 0.f, 0.f, 0.f};

    for (int kt = 0; kt < S_ / 64; ++kt) {
        const int k0 = kt * 64;
        __syncthreads();   // all waves done with prior tile's LDS
        for (int c = tid; c < 512; c += 256) {
            int row = c >> 3, cc = (c & 7) * 8;
            *(uint4*)&krs[row][cc] = *(const uint4*)&kr[base + (size_t)(k0 + row) * DM_ + cc];
            *(uint4*)&vrs[row][cc] = *(const uint4*)&vr[base + (size_t)(k0 + row) * DM_ + cc];
            *(uint4*)&kts[row][cc] = *(const uint4*)&kpt[baseT + (size_t)row * S_ + k0 + cc];
        }
        __syncthreads();

        const int tf = tflags[b * 16 + kt];   // wave-uniform

        // QK: S1 = q1@kr^T (log2 domain), S2 = q2@vr^T; B-frags shared over rt
        f32x4 s1[2][4], s2[2][4];
#pragma unroll
        for (int rt = 0; rt < 2; ++rt)
#pragma unroll
            for (int ct = 0; ct < 4; ++ct) {
                s1[rt][ct] = (f32x4){0.f, 0.f, 0.f, 0.f};
                s2[rt][ct] = (f32x4){0.f, 0.f, 0.f, 0.f};
            }
#pragma unroll
        for (int kk = 0; kk < 2; ++kk) {
            bf16x8 b1[4], b2[4];
#pragma unroll
            for (int ct = 0; ct < 4; ++ct) {
                b1[ct] = *(const bf16x8*)&krs[ct * 16 + l16][kk * 32 + quad * 8];
                b2[ct] = *(const bf16x8*)&vrs[ct * 16 + l16][kk * 32 + quad * 8];
            }
#pragma unroll
            for (int rt = 0; rt < 2; ++rt)
#pragma unroll
                for (int ct = 0; ct < 4; ++ct) {
                    s1[rt][ct] = __builtin_amdgcn_mfma_f32_16x16x32_bf16(
                        a1[rt][kk], b1[ct], s1[rt][ct], 0, 0, 0);
                    s2[rt][ct] = __builtin_amdgcn_mfma_f32_16x16x32_bf16(
                        a2[rt][kk], b2[ct], s2[rt][ct], 0, 0, 0);
                }
        }

        // mask fallback (never taken for all-ones mask; correct if taken)
        if (tf) {
#pragma unroll
            for (int rt = 0; rt < 2; ++rt)
#pragma unroll
                for (int ct = 0; ct < 4; ++ct)
#pragma unroll
                    for (int r = 0; r < 4; ++r) {
                        int qrow = q0 + w * 32 + rt * 16 + quad * 4 + r;
                        int kc   = k0 + ct * 16 + l16;
                        if (mask[((size_t)b * S_ + qrow) * S_ + kc] == 0)
                            s1[rt][ct][r] = -1e9f;
                    }
        }

        // online softmax (log2 domain)
        float tmax[2][4];
#pragma unroll
        for (int rt = 0; rt < 2; ++rt)
#pragma unroll
            for (int r = 0; r < 4; ++r) tmax[rt][r] = -1e30f;
#pragma unroll
        for (int rt = 0; rt < 2; ++rt)
#pragma unroll
            for (int ct = 0; ct < 4; ++ct)
#pragma unroll
                for (int r = 0; r < 4; ++r)
                    tmax[rt][r] = fmaxf(tmax[rt][r], s1[rt][ct][r]);
#pragma unroll
        for (int off = 1; off < 16; off <<= 1)
#pragma unroll
            for (int rt = 0; rt < 2; ++rt)
#pragma unroll
                for (int r = 0; r < 4; ++r)
                    tmax[rt][r] = fmaxf(tmax[rt][r], __shfl_xor(tmax[rt][r], off, 64));

        float alpha[2][4], newm[2][4];
#pragma unroll
        for (int rt = 0; rt < 2; ++rt)
#pragma unroll
            for (int r = 0; r < 4; ++r) {
                newm[rt][r]  = fmaxf(m_run[rt][r], tmax[rt][r]);
                alpha[rt][r] = exp2f(m_run[rt][r] - newm[rt][r]);
                m_run[rt][r] = newm[rt][r];
            }

        float psum[2][4] = {};
#pragma unroll
        for (int rt = 0; rt < 2; ++rt)
#pragma unroll
            for (int ct = 0; ct < 4; ++ct)
#pragma unroll
                for (int r = 0; r < 4; ++r) {
                    float p = exp2f(s1[rt][ct][r] - newm[rt][r]);
                    psum[rt][r] += p;
                    pts[w][rt * 16 + quad * 4 + r][ct * 16 + l16] =
                        f2bf_fast(p * s2[rt][ct][r]);
                }
#pragma unroll
        for (int off = 1; off < 16; off <<= 1)
#pragma unroll
            for (int rt = 0; rt < 2; ++rt)
#pragma unroll
                for (int r = 0; r < 4; ++r)
                    psum[rt][r] += __shfl_xor(psum[rt][r], off, 64);
#pragma unroll
        for (int rt = 0; rt < 2; ++rt)
#pragma unroll
            for (int r = 0; r < 4; ++r)
                l_run[rt][r] = l_run[rt][r] * alpha[rt][r] + psum[rt][r];
#pragma unroll
        for (int rt = 0; rt < 2; ++rt)
#pragma unroll
            for (int ct = 0; ct < 4; ++ct)
#pragma unroll
                for (int r = 0; r < 4; ++r) oacc[rt][ct][r] *= alpha[rt][r];

        // PV: O += P~ @ Kp_tile (pts same-wave DS in-order; kts shared over rt)
        {
            bf16x8 bb[2][4];
#pragma unroll
            for (int kk = 0; kk < 2; ++kk)
#pragma unroll
                for (int ct = 0; ct < 4; ++ct)
                    bb[kk][ct] = *(const bf16x8*)&kts[ct * 16 + l16][kk * 32 + quad * 8];
#pragma unroll
            for (int rt = 0; rt < 2; ++rt)
#pragma unroll
                for (int kk = 0; kk < 2; ++kk) {
                    bf16x8 a = *(const bf16x8*)&pts[w][rt * 16 + l16][kk * 32 + quad * 8];
#pragma unroll
                    for (int ct = 0; ct < 4; ++ct)
                        oacc[rt][ct] = __builtin_amdgcn_mfma_f32_16x16x32_bf16(
                            a, bb[kk][ct], oacc[rt][ct], 0, 0, 0);
                }
        }
    }

#pragma unroll
    for (int rt = 0; rt < 2; ++rt)
#pragma unroll
        for (int ct = 0; ct < 4; ++ct)
#pragma unroll
            for (int r = 0; r < 4; ++r) {
                int row = q0 + w * 32 + rt * 16 + quad * 4 + r;
                int col = ct * 16 + l16;
                float v = oacc[rt][ct][r] / l_run[rt][r];
                om[base + (size_t)row * DM_ + col] = f2bf_fast(v);
            }
}

// ---------------------------------------------------------------------------
extern "C" void kernel_launch(void* const* d_in, const int* in_sizes, int n_in,
                              void* d_out, int out_size, void* d_ws, size_t ws_size,
                              hipStream_t stream)
{
    const void* query = d_in[0];
    const void* key   = d_in[1];
    const void* value = d_in[2];
    const int*  mask  = (const int*)d_in[3];
    const void* Wq  = d_in[4];  const void* bq  = d_in[5];
    const void* Wk  = d_in[6];  const void* bk  = d_in[7];
    const void* Wv  = d_in[8];  const void* bv  = d_in[9];
    const void* Wo  = d_in[10]; const void* bo  = d_in[11];
    const void* Wkl = d_in[12]; const void* bkl = d_in[13];
    const void* Wql = d_in[14]; const void* bql = d_in[15];
    const void* Wq2 = d_in[16]; const void* bq2 = d_in[17];
    const void* Wvl = d_in[18]; const void* bvl = d_in[19];
    const void* Wel = d_in[20]; const void* bel = d_in[21];

    int* flag   = (int*)d_ws;
    int* tflags = (int*)d_ws + 4;                     // 64 ints
    u16* ws     = (u16*)((char*)d_ws + 512);
    const size_t BUF = (size_t)(B_ * S_) * DM_;       // 4M elems = 8 MB bf16
    u16* Qp  = ws + 0 * BUF;
    u16* Kp  = ws + 1 * BUF;
    u16* Vp  = ws + 2 * BUF;
    u16* krb = ws + 3 * BUF;
    u16* q1b = ws + 4 * BUF;
    u16* q2r = ws + 5 * BUF;
    u16* vrb = ws + 6 * BUF;
    u16* Om  = ws + 7 * BUF;
    u16* Qc  = ws + 8 * BUF;
    u16* Kc  = ws + 9 * BUF;
    u16* Vc  = ws + 10 * BUF;
    u16* Wbig = ws + 11 * BUF;
    u16* Wqc = Wbig + 0 * (size_t)(DM_ * DM_);
    u16* Wkc = Wbig + 1 * (size_t)(DM_ * DM_);
    u16* Wvc = Wbig + 2 * (size_t)(DM_ * DM_);
    u16* Woc = Wbig + 3 * (size_t)(DM_ * DM_);
    u16* Wsm = Wbig + 4 * (size_t)(DM_ * DM_);
    u16* Wklc = Wsm + 0 * (DK_ * DK_);
    u16* Wqlc = Wsm + 1 * (DK_ * DK_);
    u16* Welc = Wsm + 2 * (DK_ * DK_);
    u16* Wq2c = Wsm + 3 * (DK_ * DK_);
    u16* Wvlc = Wsm + 4 * (DK_ * DK_);
    u16* KpT = Vp;   // alias: Vp free after refinement batch

    const int M = B_ * S_;
    dim3 blk(256);

    detect_kernel<<<1, 64, 0, stream>>>((const u16*)query, flag);

    // fused mask-flag scan + dtype conversion
    hipMemsetAsync(tflags, 0, 64 * sizeof(int), stream);
    CvtArgs ca;
    const unsigned VIN = (unsigned)(BUF / 8);
    const unsigned VWB = (unsigned)(DM_ * DM_ / 8);
    const unsigned VWS = (unsigned)(DK_ * DK_ / 8);
    const void* srcs[NSEG] = {query, key, value, Wq, Wk, Wv, Wo, Wkl, Wql, Wel, Wq2, Wvl};
    void* dsts[NSEG] = {Qc, Kc, Vc, Wqc, Wkc, Wvc, Woc, Wklc, Wqlc, Welc, Wq2c, Wvlc};
    unsigned vcn[NSEG] = {VIN, VIN, VIN, VWB, VWB, VWB, VWB, VWS, VWS, VWS, VWS, VWS};
    unsigned off = 0;
    for (int i = 0; i < NSEG; ++i) { ca.src[i] = srcs[i]; ca.dst[i] = dsts[i]; ca.off[i] = off; off += vcn[i]; }
    ca.off[NSEG] = off;
    prep_kernel<<<dim3(512 + (off + 255) / 256), blk, 0, stream>>>(ca, off, flag, mask, tflags);

    // Q/K/V projections batched (768 blocks -> 3/CU)
    GemmBatch gqkv = {};
    gqkv.A0[0] = (const u16*)query; gqkv.A1[0] = Qc;
    gqkv.A0[1] = (const u16*)key;   gqkv.A1[1] = Kc;
    gqkv.A0[2] = (const u16*)value; gqkv.A1[2] = Vc;
    gqkv.W0[0] = (const u16*)Wq; gqkv.W1[0] = Wqc;
    gqkv.W0[1] = (const u16*)Wk; gqkv.W1[1] = Wkc;
    gqkv.W0[2] = (const u16*)Wv; gqkv.W1[2] = Wvc;
    gqkv.bias[0] = bq; gqkv.bias[1] = bk; gqkv.bias[2] = bv;
    gqkv.C[0] = Qp; gqkv.C[1] = Kp; gqkv.C[2] = Vp;
    dim3 gBig(DM_ / 128, M / 128, 3);
    gemm_async_kernel<0,1,0><<<gBig, blk, 0, stream>>>(gqkv, M, DM_, DM_, flag);

    // 4 refinements batched; g=1 chains Wql->Wel (q1b, pre-scaled by log2e)
    GemmBatch gref = {};
    gref.A0[0] = gref.A1[0] = Kp; gref.W0[0] = (const u16*)Wkl; gref.W1[0] = Wklc;
    gref.A0[1] = gref.A1[1] = Qp; gref.W0[1] = (const u16*)Wql; gref.W1[1] = Wqlc;
    gref.A0[2] = gref.A1[2] = Qp; gref.W0[2] = (const u16*)Wq2; gref.W1[2] = Wq2c;
    gref.A0[3] = gref.A1[3] = Vp; gref.W0[3] = (const u16*)Wvl; gref.W1[3] = Wvlc;
    gref.bias[0] = bkl; gref.bias[1] = bql; gref.bias[2] = bq2; gref.bias[3] = bvl;
    gref.C[0] = krb; gref.C[1] = q1b; gref.C[2] = q2r; gref.C[3] = vrb;
    gref.oscale[0] = 1.0f; gref.oscale[1] = LOG2E; gref.oscale[2] = 1.0f; gref.oscale[3] = 1.0f;
    gref.chain[0] = 0; gref.chain[1] = 1; gref.chain[2] = 0; gref.chain[3] = 0;
    gref.W20[1] = (const u16*)Wel; gref.W21[1] = Welc; gref.bias2[1] = bel;
    dim3 gSm(1, (M * H_) / 128, 4);
    gemm_small_kernel<1,1,0><<<gSm, blk, 0, stream>>>(gref, M * H_, DK_, DK_, flag);

    // Kp -> per-head transposed copy (Vp slot free after refinement batch)
    dim3 gT(S_ / 64, H_, B_);
    transpose_kernel<<<gT, blk, 0, stream>>>(Kp, KpT);

    // fused attention -> merged (B,S,DM) layout (128 q-rows per block)
    dim3 gA(S_ / 128, H_, B_);
    attn_kernel<<<gA, blk, 0, stream>>>(q1b, q2r, krb, vrb, KpT, mask, tflags, Om);

    // output projection -> d_out
    GemmBatch go = {};
    go.A0[0] = go.A1[0] = Om; go.W0[0] = (const u16*)Wo; go.W1[0] = Woc;
    go.bias[0] = bo; go.C[0] = (u16*)d_out;
    dim3 gO(DM_ / 128, M / 128, 1);
    gemm_async_kernel<0,1,1><<<gO, blk, 0, stream>>>(go, M, DM_, DM_, flag);
}

// Round 10
// 315.491 us; speedup vs baseline: 1.5124x; 1.0038x over previous
//
#include <hip/hip_runtime.h>
#include <hip/hip_bf16.h>

#define B_  4
#define S_  1024
#define DM_ 1024
#define H_  16
#define DK_ 64

typedef unsigned short u16;
typedef __attribute__((ext_vector_type(8))) short bf16x8;
typedef __attribute__((ext_vector_type(4))) float f32x4;

__device__ __forceinline__ float bf2f(u16 u) {
    union { unsigned int i; float f; } c;
    c.i = ((unsigned int)u) << 16;
    return c.f;
}
__device__ __forceinline__ u16 f2bf(float f) {
    union { float f; unsigned int i; } c;
    c.f = f;
    unsigned int x = c.i;
    unsigned int lsb = (x >> 16) & 1u;
    x += 0x7fffu + lsb;          // round-to-nearest-even
    return (u16)(x >> 16);
}
__device__ __forceinline__ u16 f2bf_fast(float f) {
    __hip_bfloat16 h = __float2bfloat16(f);   // HW cvt, RNE
    return *reinterpret_cast<u16*>(&h);
}

// async global->LDS, 16B per lane; LDS dest = wave-uniform base + lane*16
__device__ __forceinline__ void async_ld16(const u16* g, u16* l) {
    __builtin_amdgcn_global_load_lds(
        (const __attribute__((address_space(1))) unsigned int*)(const void*)g,
        (__attribute__((address_space(3))) unsigned int*)(void*)l, 16, 0, 0);
}

// ---------------------------------------------------------------------------
// Runtime dtype detection (one wave). flag=1: inputs are fp32.
// ---------------------------------------------------------------------------
__global__ void detect_kernel(const u16* __restrict__ q, int* __restrict__ flag) {
    int lane = threadIdx.x & 63;
    int cnt = 0;
#pragma unroll
    for (int i = 0; i < 4; ++i) {
        u16 u = q[2 * (lane * 4 + i)];
        int e = (u >> 7) & 0xFF;
        cnt += (e >= 100 && e <= 140) ? 1 : 0;
    }
#pragma unroll
    for (int off = 1; off < 64; off <<= 1) cnt += __shfl_xor(cnt, off, 64);
    if (lane == 0) *flag = (cnt < 128) ? 1 : 0;
}

// ---------------------------------------------------------------------------
// Fused prep: blocks [0,512) scan mask -> per-(b,k64-tile) any-zero flags
// (tflags pre-zeroed via hipMemsetAsync; dirty -> atomicOr 1). Blocks >= 512
// do packed fp32->bf16 conversion (early-out when inputs already bf16).
// ---------------------------------------------------------------------------
#define NSEG 12
struct CvtArgs {
    const void* src[NSEG];
    void*       dst[NSEG];
    unsigned    off[NSEG + 1];
};

__global__ __launch_bounds__(256) void prep_kernel(
    CvtArgs a, unsigned total, const int* __restrict__ flag,
    const int* __restrict__ mask, int* __restrict__ tflags)
{
    const int tid = threadIdx.x;
    if (blockIdx.x < 512) {
        const int bx = blockIdx.x;
        const int kt = bx & 15, b = (bx >> 4) & 3, z = bx >> 6;
        int ok = 1;
#pragma unroll
        for (int i = tid; i < 128 * 16; i += 256) {
            int row = z * 128 + (i >> 4), seg = i & 15;
            int4 m = *(const int4*)&mask[((size_t)b * S_ + row) * S_ + kt * 64 + seg * 4];
            ok &= (m.x != 0) & (m.y != 0) & (m.z != 0) & (m.w != 0);
        }
        if (!ok) atomicOr(&tflags[b * 16 + kt], 1);
        return;
    }
    if (!*flag) return;   // bf16 inputs: GEMMs read originals directly
    unsigned v = (blockIdx.x - 512) * 256 + tid;
    if (v >= total) return;
    int s = 0;
    while (s < NSEG - 1 && v >= a.off[s + 1]) ++s;
    unsigned local = v - a.off[s];
    u16* dp = (u16*)a.dst[s] + (size_t)local * 8;
    const float* sp = (const float*)a.src[s] + (size_t)local * 8;
    float4 x = *(const float4*)sp, y = *(const float4*)(sp + 4);
    u16 t[8] = {f2bf(x.x), f2bf(x.y), f2bf(x.z), f2bf(x.w),
                f2bf(y.x), f2bf(y.y), f2bf(y.z), f2bf(y.w)};
    *(uint4*)dp = *(uint4*)t;
}

// ---------------------------------------------------------------------------
// Per-head transpose: Kp (b,s,h,d) -> KpT[((b*H+h)*DK + d)*S + s].
// ---------------------------------------------------------------------------
__global__ __launch_bounds__(256) void transpose_kernel(
    const u16* __restrict__ kp, u16* __restrict__ kpt)
{
    __shared__ u16 T[64][65];
    const int s0 = blockIdx.x * 64, h = blockIdx.y, b = blockIdx.z;
    const int tid = threadIdx.x;
    const size_t base = (size_t)b * S_ * DM_ + (size_t)h * DK_;
    for (int c = tid; c < 512; c += 256) {
        int row = c >> 3, cc = (c & 7) * 8;
        union { uint4 v; u16 u[8]; } x;
        x.v = *(const uint4*)&kp[base + (size_t)(s0 + row) * DM_ + cc];
#pragma unroll
        for (int j = 0; j < 8; ++j) T[row][cc + j] = x.u[j];
    }
    __syncthreads();
    const size_t baseT = (size_t)(b * H_ + h) * DK_ * S_;
    for (int c = tid; c < 512; c += 256) {
        int d = c >> 3, ss = (c & 7) * 8;
        u16 t[8];
#pragma unroll
        for (int j = 0; j < 8; ++j) t[j] = T[ss + j][d];
        *(uint4*)&kpt[baseT + (size_t)d * S_ + s0 + ss] = *(uint4*)t;
    }
}

// ---------------------------------------------------------------------------
// QKV projection + fused per-head refinements. 128x128 tile, BK=64, async
// global->LDS staging, XOR column-group swizzle (m97 structure). After the
// K-loop each wave's 64x64 quadrant is ONE head's complete column block for
// 64 rows, so the row-local 64x64 refinements run entirely in the epilogue:
// C-layout acc -> per-wave LDS region (A-layout swizzled) -> MFMA with
// weight B-frags read straight from global (L2-hot, shared across heads).
// z=0 (Q): emits q1b (Wql->Wel chain) + q2r. z=1 (K): Kp + krb. z=2: vrb.
// ---------------------------------------------------------------------------
struct QKVArgs {
    const u16* A0[3]; const u16* A1[3];
    const u16* W0[3]; const u16* W1[3];
    const void* bias[3];
    const u16* R10[3]; const u16* R11[3];   // Wql, Wkl, Wvl
    const void* rb1[3];                      // bql, bkl, bvl
    const u16* R20; const u16* R21; const void* rb2;   // Wel, bel
    const u16* R30; const u16* R31; const void* rb3;   // Wq2, bq2
    u16 *Kp, *q1b, *q2r, *krb, *vrb;
};

__global__ __launch_bounds__(256, 3) void qkv_fused_kernel(
    QKVArgs a, const int* __restrict__ flag)
{
    __shared__ __align__(16) u16 smem[16384];   // 32 KB: As+Ws; epilogue 4x8KB/wave
    u16 (*As)[64] = (u16(*)[64])smem;
    u16 (*Ws)[64] = (u16(*)[64])(smem + 8192);

    const int z = blockIdx.z;
    const int f = *flag;
    const u16* __restrict__ A = f ? a.A1[z] : a.A0[z];
    const u16* __restrict__ W = f ? a.W1[z] : a.W0[z];
    const void* biasp = a.bias[z];

    const int m0   = blockIdx.y * 128;
    const int n0   = blockIdx.x * 128;
    const int tid  = threadIdx.x;
    const int w    = tid >> 6;
    const int lane = tid & 63;
    const int l16  = lane & 15;
    const int quad = lane >> 4;
    const int wr   = (w >> 1) * 64;
    const int wc   = (w & 1) * 64;

    const int srow = lane >> 3;
    const int sgrp = (lane & 7) ^ srow;

    f32x4 acc[4][4];
#pragma unroll
    for (int rt = 0; rt < 4; ++rt)
#pragma unroll
        for (int ct = 0; ct < 4; ++ct) acc[rt][ct] = (f32x4){0.f, 0.f, 0.f, 0.f};

    for (int k0 = 0; k0 < DM_; k0 += 64) {
#pragma unroll
        for (int s = 0; s < 4; ++s) {
            int seg = w * 4 + s;
            async_ld16(&A[(size_t)(m0 + seg * 8 + srow) * DM_ + k0 + sgrp * 8],
                       &As[seg * 8][0]);
            async_ld16(&W[(size_t)(n0 + seg * 8 + srow) * DM_ + k0 + sgrp * 8],
                       &Ws[seg * 8][0]);
        }
        __syncthreads();
#pragma unroll
        for (int kk = 0; kk < 2; ++kk) {
            const int p = (kk * 4 + quad) ^ (l16 & 7);
            bf16x8 av[4], bv[4];
#pragma unroll
            for (int rt = 0; rt < 4; ++rt)
                av[rt] = *(const bf16x8*)&As[wr + rt * 16 + l16][p * 8];
#pragma unroll
            for (int ct = 0; ct < 4; ++ct)
                bv[ct] = *(const bf16x8*)&Ws[wc + ct * 16 + l16][p * 8];
#pragma unroll
            for (int rt = 0; rt < 4; ++rt)
#pragma unroll
                for (int ct = 0; ct < 4; ++ct)
                    acc[rt][ct] = __builtin_amdgcn_mfma_f32_16x16x32_bf16(
                        av[rt], bv[ct], acc[rt][ct], 0, 0, 0);
        }
        __syncthreads();   // trailing barrier: all waves done reading As/Ws
    }

    // ---- fused refinement epilogue (per-wave private LDS region) ----
    const int hcol = n0 + wc;                       // = head * 64
    u16 (*Es)[64] = (u16(*)[64])(smem + w * 4096);

    // projected tile (+bias, bf16) -> Es in A-layout swizzle; z==1 also -> Kp
#pragma unroll
    for (int ct = 0; ct < 4; ++ct) {
        int col = hcol + ct * 16 + l16;
        float bv = f ? ((const float*)biasp)[col] : bf2f(((const u16*)biasp)[col]);
#pragma unroll
        for (int rt = 0; rt < 4; ++rt)
#pragma unroll
            for (int r = 0; r < 4; ++r) {
                int ml = rt * 16 + quad * 4 + r;
                int cl = ct * 16 + l16;
                u16 bb = f2bf(acc[rt][ct][r] + bv);
                if (z == 1) a.Kp[(size_t)(m0 + wr + ml) * DM_ + col] = bb;
                Es[ml][((((cl >> 3) ^ (ml & 7)) << 3) | (cl & 7))] = bb;
            }
    }

    // A-frags of the projected tile (same-wave DS in-order; no barrier needed)
    bf16x8 af[4][2];
#pragma unroll
    for (int rt = 0; rt < 4; ++rt)
#pragma unroll
        for (int kk = 0; kk < 2; ++kk)
            af[rt][kk] = *(const bf16x8*)
                &Es[rt * 16 + l16][(((kk * 4 + quad) ^ (l16 & 7)) << 3)];

    // stage-1 weight B-frags from global (64x64, L2-hot)
    const u16* R1 = f ? a.R11[z] : a.R10[z];
    bf16x8 wb[2][4];
#pragma unroll
    for (int kk = 0; kk < 2; ++kk)
#pragma unroll
        for (int ct = 0; ct < 4; ++ct)
            wb[kk][ct] = *(const bf16x8*)
                &R1[(size_t)(ct * 16 + l16) * 64 + kk * 32 + quad * 8];

    f32x4 r1[4][4];
#pragma unroll
    for (int rt = 0; rt < 4; ++rt)
#pragma unroll
        for (int ct = 0; ct < 4; ++ct) r1[rt][ct] = (f32x4){0.f, 0.f, 0.f, 0.f};
#pragma unroll
    for (int kk = 0; kk < 2; ++kk)
#pragma unroll
        for (int rt = 0; rt < 4; ++rt)
#pragma unroll
            for (int ct = 0; ct < 4; ++ct)
                r1[rt][ct] = __builtin_amdgcn_mfma_f32_16x16x32_bf16(
                    af[rt][kk], wb[kk][ct], r1[rt][ct], 0, 0, 0);

    if (z != 0) {
        // single-stage: krb (z==1) or vrb (z==2) = relu(r1 + rb1)
        const void* rb = a.rb1[z];
        u16* out = (z == 1) ? a.krb : a.vrb;
#pragma unroll
        for (int ct = 0; ct < 4; ++ct) {
            int cl = ct * 16 + l16;
            float bv = f ? ((const float*)rb)[cl] : bf2f(((const u16*)rb)[cl]);
#pragma unroll
            for (int rt = 0; rt < 4; ++rt)
#pragma unroll
                for (int r = 0; r < 4; ++r) {
                    float v = r1[rt][ct][r] + bv;
                    v = v > 0.f ? v : 0.f;
                    out[(size_t)(m0 + wr + rt * 16 + quad * 4 + r) * DM_ + hcol + cl]
                        = f2bf(v);
                }
        }
    } else {
        // q1a = relu(r1 + bql) -> Es (round-trip for stage 2)
        {
            const void* rb = a.rb1[0];
#pragma unroll
            for (int ct = 0; ct < 4; ++ct) {
                int cl = ct * 16 + l16;
                float bv = f ? ((const float*)rb)[cl] : bf2f(((const u16*)rb)[cl]);
#pragma unroll
                for (int rt = 0; rt < 4; ++rt)
#pragma unroll
                    for (int r = 0; r < 4; ++r) {
                        float v = r1[rt][ct][r] + bv;
                        v = v > 0.f ? v : 0.f;
                        int ml = rt * 16 + quad * 4 + r;
                        Es[ml][((((cl >> 3) ^ (ml & 7)) << 3) | (cl & 7))] = f2bf(v);
                    }
            }
        }
        // q2r = relu(proj @ Wq2^T + bq2)  (reuses af while Es writes land)
        {
            const u16* R3 = f ? a.R31 : a.R30;
#pragma unroll
            for (int kk = 0; kk < 2; ++kk)
#pragma unroll
                for (int ct = 0; ct < 4; ++ct)
                    wb[kk][ct] = *(const bf16x8*)
                        &R3[(size_t)(ct * 16 + l16) * 64 + kk * 32 + quad * 8];
            f32x4 r3[4][4];
#pragma unroll
            for (int rt = 0; rt < 4; ++rt)
#pragma unroll
                for (int ct = 0; ct < 4; ++ct) r3[rt][ct] = (f32x4){0.f, 0.f, 0.f, 0.f};
#pragma unroll
            for (int kk = 0; kk < 2; ++kk)
#pragma unroll
                for (int rt = 0; rt < 4; ++rt)
#pragma unroll
                    for (int ct = 0; ct < 4; ++ct)
                        r3[rt][ct] = __builtin_amdgcn_mfma_f32_16x16x32_bf16(
                            af[rt][kk], wb[kk][ct], r3[rt][ct], 0, 0, 0);
            const void* rb = a.rb3;
#pragma unroll
            for (int ct = 0; ct < 4; ++ct) {
                int cl = ct * 16 + l16;
                float bv = f ? ((const float*)rb)[cl] : bf2f(((const u16*)rb)[cl]);
#pragma unroll
                for (int rt = 0; rt < 4; ++rt)
#pragma unroll
                    for (int r = 0; r < 4; ++r) {
                        float v = r3[rt][ct][r] + bv;
                        v = v > 0.f ? v : 0.f;
                        a.q2r[(size_t)(m0 + wr + rt * 16 + quad * 4 + r) * DM_
                              + hcol + cl] = f2bf(v);
                    }
            }
        }
        // q1b = relu(q1a @ Wel^T + bel)
        {
#pragma unroll
            for (int rt = 0; rt < 4; ++rt)
#pragma unroll
                for (int kk = 0; kk < 2; ++kk)
                    af[rt][kk] = *(const bf16x8*)
                        &Es[rt * 16 + l16][(((kk * 4 + quad) ^ (l16 & 7)) << 3)];
            const u16* R2 = f ? a.R21 : a.R20;
#pragma unroll
            for (int kk = 0; kk < 2; ++kk)
#pragma unroll
                for (int ct = 0; ct < 4; ++ct)
                    wb[kk][ct] = *(const bf16x8*)
                        &R2[(size_t)(ct * 16 + l16) * 64 + kk * 32 + quad * 8];
            f32x4 r2[4][4];
#pragma unroll
            for (int rt = 0; rt < 4; ++rt)
#pragma unroll
                for (int ct = 0; ct < 4; ++ct) r2[rt][ct] = (f32x4){0.f, 0.f, 0.f, 0.f};
#pragma unroll
            for (int kk = 0; kk < 2; ++kk)
#pragma unroll
                for (int rt = 0; rt < 4; ++rt)
#pragma unroll
                    for (int ct = 0; ct < 4; ++ct)
                        r2[rt][ct] = __builtin_amdgcn_mfma_f32_16x16x32_bf16(
                            af[rt][kk], wb[kk][ct], r2[rt][ct], 0, 0, 0);
            const void* rb = a.rb2;
#pragma unroll
            for (int ct = 0; ct < 4; ++ct) {
                int cl = ct * 16 + l16;
                float bv = f ? ((const float*)rb)[cl] : bf2f(((const u16*)rb)[cl]);
#pragma unroll
                for (int rt = 0; rt < 4; ++rt)
#pragma unroll
                    for (int r = 0; r < 4; ++r) {
                        float v = r2[rt][ct][r] + bv;
                        v = v > 0.f ? v : 0.f;
                        a.q1b[(size_t)(m0 + wr + rt * 16 + quad * 4 + r) * DM_
                              + hcol + cl] = f2bf(v);
                    }
            }
        }
    }
}

// ---------------------------------------------------------------------------
// Output-projection GEMM (m97 structure), dtype-dynamic bias/out.
// ---------------------------------------------------------------------------
__global__ __launch_bounds__(256, 3) void gemm_async_kernel(
    const u16* __restrict__ Ain, const u16* __restrict__ W0,
    const u16* __restrict__ W1, const void* __restrict__ biasp,
    void* __restrict__ Cp, const int* __restrict__ flag)
{
    __shared__ __align__(16) u16 As[128][64];
    __shared__ __align__(16) u16 Ws[128][64];

    const int f = *flag;
    const u16* __restrict__ W = f ? W1 : W0;

    const int m0   = blockIdx.y * 128;
    const int n0   = blockIdx.x * 128;
    const int tid  = threadIdx.x;
    const int w    = tid >> 6;
    const int lane = tid & 63;
    const int l16  = lane & 15;
    const int quad = lane >> 4;
    const int wr   = (w >> 1) * 64;
    const int wc   = (w & 1) * 64;

    const int srow = lane >> 3;
    const int sgrp = (lane & 7) ^ srow;

    f32x4 acc[4][4];
#pragma unroll
    for (int rt = 0; rt < 4; ++rt)
#pragma unroll
        for (int ct = 0; ct < 4; ++ct) acc[rt][ct] = (f32x4){0.f, 0.f, 0.f, 0.f};

    for (int k0 = 0; k0 < DM_; k0 += 64) {
#pragma unroll
        for (int s = 0; s < 4; ++s) {
            int seg = w * 4 + s;
            async_ld16(&Ain[(size_t)(m0 + seg * 8 + srow) * DM_ + k0 + sgrp * 8],
                       &As[seg * 8][0]);
            async_ld16(&W[(size_t)(n0 + seg * 8 + srow) * DM_ + k0 + sgrp * 8],
                       &Ws[seg * 8][0]);
        }
        __syncthreads();
#pragma unroll
        for (int kk = 0; kk < 2; ++kk) {
            const int p = (kk * 4 + quad) ^ (l16 & 7);
            bf16x8 av[4], bv[4];
#pragma unroll
            for (int rt = 0; rt < 4; ++rt)
                av[rt] = *(const bf16x8*)&As[wr + rt * 16 + l16][p * 8];
#pragma unroll
            for (int ct = 0; ct < 4; ++ct)
                bv[ct] = *(const bf16x8*)&Ws[wc + ct * 16 + l16][p * 8];
#pragma unroll
            for (int rt = 0; rt < 4; ++rt)
#pragma unroll
                for (int ct = 0; ct < 4; ++ct)
                    acc[rt][ct] = __builtin_amdgcn_mfma_f32_16x16x32_bf16(
                        av[rt], bv[ct], acc[rt][ct], 0, 0, 0);
        }
        __syncthreads();
    }

#pragma unroll
    for (int ct = 0; ct < 4; ++ct) {
        int col = n0 + wc + ct * 16 + l16;
        float bv = f ? ((const float*)biasp)[col] : bf2f(((const u16*)biasp)[col]);
#pragma unroll
        for (int rt = 0; rt < 4; ++rt)
#pragma unroll
            for (int r = 0; r < 4; ++r) {
                int row = m0 + wr + rt * 16 + quad * 4 + r;
                float v = acc[rt][ct][r] + bv;
                size_t idx = (size_t)row * DM_ + col;
                if (f) ((float*)Cp)[idx] = v;
                else   ((u16*)Cp)[idx]   = f2bf(v);
            }
    }
}

// ---------------------------------------------------------------------------
// Fused attention (R7 structure — known-good 77.7 µs): 2-barrier VGPR
// staging, 128 q-rows/block (wave owns 32 rows, 2 row-tiles), __expf
// softmax (native v_exp path; libm exp2f regressed 10 µs in R8/R9).
// Mask via per-(b,k-tile) flags; dirty-tile fallback reads mask from global.
// ---------------------------------------------------------------------------
__global__ __launch_bounds__(256, 2) void attn_kernel(
    const u16* __restrict__ q1, const u16* __restrict__ q2,
    const u16* __restrict__ kr, const u16* __restrict__ vr,
    const u16* __restrict__ kpt, const int* __restrict__ mask,
    const int* __restrict__ tflags, u16* __restrict__ om)
{
    __shared__ __align__(16) u16 krs[64][72];
    __shared__ __align__(16) u16 vrs[64][72];
    __shared__ __align__(16) u16 kts[64][72];      // KpT tile: rows d, cols k
    __shared__ __align__(16) u16 pts[4][32][72];   // per-wave P~ staging

    const int qt   = blockIdx.x;
    const int h    = blockIdx.y;
    const int b    = blockIdx.z;
    const int q0   = qt * 128;
    const int tid  = threadIdx.x;
    const int w    = tid >> 6;
    const int lane = tid & 63;
    const int l16  = lane & 15;
    const int quad = lane >> 4;

    const size_t base  = (size_t)b * S_ * DM_ + (size_t)h * DK_;
    const size_t baseT = (size_t)(b * H_ + h) * DK_ * S_;

    bf16x8 a1[2][2], a2[2][2];
#pragma unroll
    for (int rt = 0; rt < 2; ++rt) {
        const int qrow = q0 + w * 32 + rt * 16 + l16;
#pragma unroll
        for (int kk = 0; kk < 2; ++kk) {
            a1[rt][kk] = *(const bf16x8*)&q1[base + (size_t)qrow * DM_ + kk * 32 + quad * 8];
            a2[rt][kk] = *(const bf16x8*)&q2[base + (size_t)qrow * DM_ + kk * 32 + quad * 8];
        }
    }

    float m_run[2][4], l_run[2][4];
    f32x4 oacc[2][4];
#pragma unroll
    for (int rt = 0; rt < 2; ++rt)
#pragma unroll
        for (int r = 0; r < 4; ++r) { m_run[rt][r] = -1e30f; l_run[rt][r] = 0.f; }
#pragma unroll
    for (int rt = 0; rt < 2; ++rt)
#pragma unroll
        for (int ct = 0; ct < 4; ++ct) oacc[rt][ct] = (f32x4){0.f, 0.f, 0.f, 0.f};

    for (int kt = 0; kt < S_ / 64; ++kt) {
        const int k0 = kt * 64;
        __syncthreads();
        for (int c = tid; c < 512; c += 256) {
            int row = c >> 3, cc = (c & 7) * 8;
            *(uint4*)&krs[row][cc] = *(const uint4*)&kr[base + (size_t)(k0 + row) * DM_ + cc];
            *(uint4*)&vrs[row][cc] = *(const uint4*)&vr[base + (size_t)(k0 + row) * DM_ + cc];
            *(uint4*)&kts[row][cc] = *(const uint4*)&kpt[baseT + (size_t)row * S_ + k0 + cc];
        }
        __syncthreads();

        const int tf = tflags[b * 16 + kt];

        f32x4 s1[2][4], s2[2][4];
#pragma unroll
        for (int rt = 0; rt < 2; ++rt)
#pragma unroll
            for (int ct = 0; ct < 4; ++ct) {
                s1[rt][ct] = (f32x4){0.f, 0.f, 0.f, 0.f};
                s2[rt][ct] = (f32x4){0.f, 0.f, 0.f, 0.f};
            }
#pragma unroll
        for (int kk = 0; kk < 2; ++kk) {
            bf16x8 b1[4], b2[4];
#pragma unroll
            for (int ct = 0; ct < 4; ++ct) {
                b1[ct] = *(const bf16x8*)&krs[ct * 16 + l16][kk * 32 + quad * 8];
                b2[ct] = *(const bf16x8*)&vrs[ct * 16 + l16][kk * 32 + quad * 8];
            }
#pragma unroll
            for (int rt = 0; rt < 2; ++rt)
#pragma unroll
                for (int ct = 0; ct < 4; ++ct) {
                    s1[rt][ct] = __builtin_amdgcn_mfma_f32_16x16x32_bf16(
                        a1[rt][kk], b1[ct], s1[rt][ct], 0, 0, 0);
                    s2[rt][ct] = __builtin_amdgcn_mfma_f32_16x16x32_bf16(
                        a2[rt][kk], b2[ct], s2[rt][ct], 0, 0, 0);
                }
        }

        if (tf) {
#pragma unroll
            for (int rt = 0; rt < 2; ++rt)
#pragma unroll
                for (int ct = 0; ct < 4; ++ct)
#pragma unroll
                    for (int r = 0; r < 4; ++r) {
                        int qrow = q0 + w * 32 + rt * 16 + quad * 4 + r;
                        int kc   = k0 + ct * 16 + l16;
                        if (mask[((size_t)b * S_ + qrow) * S_ + kc] == 0)
                            s1[rt][ct][r] = -1e9f;
                    }
        }

        float tmax[2][4];
#pragma unroll
        for (int rt = 0; rt < 2; ++rt)
#pragma unroll
            for (int r = 0; r < 4; ++r) tmax[rt][r] = -1e30f;
#pragma unroll
        for (int rt = 0; rt < 2; ++rt)
#pragma unroll
            for (int ct = 0; ct < 4; ++ct)
#pragma unroll
                for (int r = 0; r < 4; ++r)
                    tmax[rt][r] = fmaxf(tmax[rt][r], s1[rt][ct][r]);
#pragma unroll
        for (int off = 1; off < 16; off <<= 1)
#pragma unroll
            for (int rt = 0; rt < 2; ++rt)
#pragma unroll
                for (int r = 0; r < 4; ++r)
                    tmax[rt][r] = fmaxf(tmax[rt][r], __shfl_xor(tmax[rt][r], off, 64));

        float alpha[2][4], newm[2][4];
#pragma unroll
        for (int rt = 0; rt < 2; ++rt)
#pragma unroll
            for (int r = 0; r < 4; ++r) {
                newm[rt][r]  = fmaxf(m_run[rt][r], tmax[rt][r]);
                alpha[rt][r] = __expf(m_run[rt][r] - newm[rt][r]);
                m_run[rt][r] = newm[rt][r];
            }

        float psum[2][4] = {};
#pragma unroll
        for (int rt = 0; rt < 2; ++rt)
#pragma unroll
            for (int ct = 0; ct < 4; ++ct)
#pragma unroll
                for (int r = 0; r < 4; ++r) {
                    float p = __expf(s1[rt][ct][r] - newm[rt][r]);
                    psum[rt][r] += p;
                    pts[w][rt * 16 + quad * 4 + r][ct * 16 + l16] =
                        f2bf_fast(p * s2[rt][ct][r]);
                }
#pragma unroll
        for (int off = 1; off < 16; off <<= 1)
#pragma unroll
            for (int rt = 0; rt < 2; ++rt)
#pragma unroll
                for (int r = 0; r < 4; ++r)
                    psum[rt][r] += __shfl_xor(psum[rt][r], off, 64);
#pragma unroll
        for (int rt = 0; rt < 2; ++rt)
#pragma unroll
            for (int r = 0; r < 4; ++r)
                l_run[rt][r] = l_run[rt][r] * alpha[rt][r] + psum[rt][r];
#pragma unroll
        for (int rt = 0; rt < 2; ++rt)
#pragma unroll
            for (int ct = 0; ct < 4; ++ct)
#pragma unroll
                for (int r = 0; r < 4; ++r) oacc[rt][ct][r] *= alpha[rt][r];

        {
            bf16x8 bb[2][4];
#pragma unroll
            for (int kk = 0; kk < 2; ++kk)
#pragma unroll
                for (int ct = 0; ct < 4; ++ct)
                    bb[kk][ct] = *(const bf16x8*)&kts[ct * 16 + l16][kk * 32 + quad * 8];
#pragma unroll
            for (int rt = 0; rt < 2; ++rt)
#pragma unroll
                for (int kk = 0; kk < 2; ++kk) {
                    bf16x8 a = *(const bf16x8*)&pts[w][rt * 16 + l16][kk * 32 + quad * 8];
#pragma unroll
                    for (int ct = 0; ct < 4; ++ct)
                        oacc[rt][ct] = __builtin_amdgcn_mfma_f32_16x16x32_bf16(
                            a, bb[kk][ct], oacc[rt][ct], 0, 0, 0);
                }
        }
    }

#pragma unroll
    for (int rt = 0; rt < 2; ++rt)
#pragma unroll
        for (int ct = 0; ct < 4; ++ct)
#pragma unroll
            for (int r = 0; r < 4; ++r) {
                int row = q0 + w * 32 + rt * 16 + quad * 4 + r;
                int col = ct * 16 + l16;
                float v = oacc[rt][ct][r] / l_run[rt][r];
                om[base + (size_t)row * DM_ + col] = f2bf_fast(v);
            }
}

// ---------------------------------------------------------------------------
extern "C" void kernel_launch(void* const* d_in, const int* in_sizes, int n_in,
                              void* d_out, int out_size, void* d_ws, size_t ws_size,
                              hipStream_t stream)
{
    const void* query = d_in[0];
    const void* key   = d_in[1];
    const void* value = d_in[2];
    const int*  mask  = (const int*)d_in[3];
    const void* Wq  = d_in[4];  const void* bq  = d_in[5];
    const void* Wk  = d_in[6];  const void* bk  = d_in[7];
    const void* Wv  = d_in[8];  const void* bv  = d_in[9];
    const void* Wo  = d_in[10]; const void* bo  = d_in[11];
    const void* Wkl = d_in[12]; const void* bkl = d_in[13];
    const void* Wql = d_in[14]; const void* bql = d_in[15];
    const void* Wq2 = d_in[16]; const void* bq2 = d_in[17];
    const void* Wvl = d_in[18]; const void* bvl = d_in[19];
    const void* Wel = d_in[20]; const void* bel = d_in[21];

    int* flag   = (int*)d_ws;
    int* tflags = (int*)d_ws + 4;                     // 64 ints
    u16* ws     = (u16*)((char*)d_ws + 512);
    const size_t BUF = (size_t)(B_ * S_) * DM_;       // 4M elems = 8 MB bf16
    u16* Kp  = ws + 0 * BUF;
    u16* krb = ws + 1 * BUF;
    u16* q1b = ws + 2 * BUF;
    u16* q2r = ws + 3 * BUF;
    u16* vrb = ws + 4 * BUF;
    u16* Om  = ws + 5 * BUF;
    u16* KpT = ws + 6 * BUF;
    u16* Qc  = ws + 7 * BUF;
    u16* Kc  = ws + 8 * BUF;
    u16* Vc  = ws + 9 * BUF;
    u16* Wbig = ws + 10 * BUF;
    u16* Wqc = Wbig + 0 * (size_t)(DM_ * DM_);
    u16* Wkc = Wbig + 1 * (size_t)(DM_ * DM_);
    u16* Wvc = Wbig + 2 * (size_t)(DM_ * DM_);
    u16* Woc = Wbig + 3 * (size_t)(DM_ * DM_);
    u16* Wsm = Wbig + 4 * (size_t)(DM_ * DM_);
    u16* Wklc = Wsm + 0 * (DK_ * DK_);
    u16* Wqlc = Wsm + 1 * (DK_ * DK_);
    u16* Welc = Wsm + 2 * (DK_ * DK_);
    u16* Wq2c = Wsm + 3 * (DK_ * DK_);
    u16* Wvlc = Wsm + 4 * (DK_ * DK_);

    const int M = B_ * S_;
    dim3 blk(256);

    detect_kernel<<<1, 64, 0, stream>>>((const u16*)query, flag);

    // fused mask-flag scan + dtype conversion
    hipMemsetAsync(tflags, 0, 64 * sizeof(int), stream);
    CvtArgs ca;
    const unsigned VIN = (unsigned)(BUF / 8);
    const unsigned VWB = (unsigned)(DM_ * DM_ / 8);
    const unsigned VWS = (unsigned)(DK_ * DK_ / 8);
    const void* srcs[NSEG] = {query, key, value, Wq, Wk, Wv, Wo, Wkl, Wql, Wel, Wq2, Wvl};
    void* dsts[NSEG] = {Qc, Kc, Vc, Wqc, Wkc, Wvc, Woc, Wklc, Wqlc, Welc, Wq2c, Wvlc};
    unsigned vcn[NSEG] = {VIN, VIN, VIN, VWB, VWB, VWB, VWB, VWS, VWS, VWS, VWS, VWS};
    unsigned off = 0;
    for (int i = 0; i < NSEG; ++i) { ca.src[i] = srcs[i]; ca.dst[i] = dsts[i]; ca.off[i] = off; off += vcn[i]; }
    ca.off[NSEG] = off;
    prep_kernel<<<dim3(512 + (off + 255) / 256), blk, 0, stream>>>(ca, off, flag, mask, tflags);

    // Q/K/V projections + fused per-head refinements (768 blocks)
    QKVArgs qa = {};
    qa.A0[0] = (const u16*)query; qa.A1[0] = Qc;
    qa.A0[1] = (const u16*)key;   qa.A1[1] = Kc;
    qa.A0[2] = (const u16*)value; qa.A1[2] = Vc;
    qa.W0[0] = (const u16*)Wq; qa.W1[0] = Wqc;
    qa.W0[1] = (const u16*)Wk; qa.W1[1] = Wkc;
    qa.W0[2] = (const u16*)Wv; qa.W1[2] = Wvc;
    qa.bias[0] = bq; qa.bias[1] = bk; qa.bias[2] = bv;
    qa.R10[0] = (const u16*)Wql; qa.R11[0] = Wqlc; qa.rb1[0] = bql;
    qa.R10[1] = (const u16*)Wkl; qa.R11[1] = Wklc; qa.rb1[1] = bkl;
    qa.R10[2] = (const u16*)Wvl; qa.R11[2] = Wvlc; qa.rb1[2] = bvl;
    qa.R20 = (const u16*)Wel; qa.R21 = Welc; qa.rb2 = bel;
    qa.R30 = (const u16*)Wq2; qa.R31 = Wq2c; qa.rb3 = bq2;
    qa.Kp = Kp; qa.q1b = q1b; qa.q2r = q2r; qa.krb = krb; qa.vrb = vrb;
    dim3 gBig(DM_ / 128, M / 128, 3);
    qkv_fused_kernel<<<gBig, blk, 0, stream>>>(qa, flag);

    // Kp -> per-head transposed copy
    dim3 gT(S_ / 64, H_, B_);
    transpose_kernel<<<gT, blk, 0, stream>>>(Kp, KpT);

    // fused attention -> merged (B,S,DM) layout (128 q-rows per block)
    dim3 gA(S_ / 128, H_, B_);
    attn_kernel<<<gA, blk, 0, stream>>>(q1b, q2r, krb, vrb, KpT, mask, tflags, Om);

    // output projection -> d_out
    dim3 gO(DM_ / 128, M / 128);
    gemm_async_kernel<<<gO, blk, 0, stream>>>(Om, (const u16*)Wo, Woc, bo, d_out, flag);
}